// Round 1
// baseline (4559.140 us; speedup 1.0000x reference)
//
#include <hip/hip_runtime.h>
#include <cmath>

#define RTOT 8192        // B*C rows
#define NDWT 722         // SEQ_LEN/2+2
#define LSEQ 1440
#define NHEAD 362        // PRED_LEN/2+2
#define NFREQ 362

__constant__ float c_lo[6] = {0.035226291882100656f, -0.08544127388224149f, -0.13501102001039084f,
                              0.4598775021193313f, 0.8068915093133388f, 0.3326705529509569f};
__constant__ float c_hi[6] = {-0.3326705529509569f, 0.8068915093133388f, -0.4598775021193313f,
                              -0.13501102001039084f, 0.08544127388224149f, 0.035226291882100656f};

// ---------------- twiddle table: W^m = exp(-2*pi*i*m/722) ----------------
__global__ void wtab_kernel(float2* __restrict__ Wtab) {
    int m = blockIdx.x * blockDim.x + threadIdx.x;
    if (m < NDWT) {
        double ang = -2.0 * 3.141592653589793238462643383279502884 * (double)m / (double)NDWT;
        Wtab[m] = make_float2((float)cos(ang), (float)sin(ang));
    }
}

// ---------------- DWT: x (64,1440,128) -> ac0, dc0 (8192,722) ----------------
// ac0[t] = sum_j lo[j] * x[2t+1-j]  (zero-padded)
__global__ __launch_bounds__(512) void dwt_kernel(const float* __restrict__ x,
                                                  float* __restrict__ ac0,
                                                  float* __restrict__ dc0) {
    int b = blockIdx.x;
    int c = threadIdx.x;                       // 0..127
    int t0 = blockIdx.y * 16 + threadIdx.y * 4;
    for (int i = 0; i < 4; i++) {
        int t = t0 + i;
        if (t >= NDWT) break;
        float slo = 0.f, shi = 0.f;
        #pragma unroll
        for (int j = 0; j < 6; j++) {
            int l = 2 * t + 1 - j;
            float v = (l >= 0 && l < LSEQ) ? x[((size_t)b * LSEQ + l) * 128 + c] : 0.f;
            slo += v * c_lo[j];
            shi += v * c_hi[j];
        }
        size_t o = ((size_t)b * 128 + c) * NDWT + t;
        ac0[o] = slo;
        dc0[o] = shi;
    }
}

__device__ __forceinline__ float blockSum256(float v, float* red) {
    #pragma unroll
    for (int o = 32; o > 0; o >>= 1) v += __shfl_down(v, o, 64);
    int lane = threadIdx.x & 63, wid = threadIdx.x >> 6;
    __syncthreads();                 // protect red from previous use
    if (lane == 0) red[wid] = v;
    __syncthreads();
    return red[0] + red[1] + red[2] + red[3];
}

// ---------------- per-row: inst_norm(ac0), mov_norm(ac0), mov_norm(dc0), row-means ----------------
__global__ __launch_bounds__(256) void rowstats_kernel(
    const float* __restrict__ ac0in, const float* __restrict__ dc0in,
    float* __restrict__ acn,   // may alias ac0in (row staged in LDS first)
    float* __restrict__ acp, float* __restrict__ m_ac, float* __restrict__ s_ac,
    float* __restrict__ dcp, float* __restrict__ m_dc, float* __restrict__ s_dc,
    float* __restrict__ stat /* [4][8192]: m_all_ac, s_all_ac, m_all_dc, s_all_dc */) {
    __shared__ float row[NDWT];
    __shared__ float xc[NDWT];
    __shared__ float pool[698];
    __shared__ float red[4];
    const int r = blockIdx.x, tid = threadIdx.x;
    const size_t base = (size_t)r * NDWT;

    // ================= AC =================
    for (int i = tid; i < NDWT; i += 256) row[i] = ac0in[base + i];
    __syncthreads();
    float s = 0.f;
    for (int i = tid; i < NDWT; i += 256) s += row[i];
    float mean = blockSum256(s, red) * (1.f / 722.f);
    s = 0.f;
    for (int i = tid; i < NDWT; i += 256) s += row[i] - mean;
    float m2 = blockSum256(s, red) * (1.f / 722.f);
    s = 0.f;
    for (int i = tid; i < NDWT; i += 256) { float d = row[i] - mean - m2; s += d * d; }
    float var = blockSum256(s, red) * (1.f / 722.f);
    float inv = 1.f / sqrtf(var + 1e-5f);
    for (int i = tid; i < NDWT; i += 256) acn[base + i] = (row[i] - mean) * inv;

    for (int i = tid; i < 698; i += 256) {
        float p = 0.f;
        for (int j = 0; j < 25; j++) p += row[i + j];
        pool[i] = p * (1.f / 25.f);
    }
    __syncthreads();
    float msum = 0.f;
    for (int l = tid; l < NDWT; l += 256) {
        int pi = l - 12; pi = pi < 0 ? 0 : (pi > 697 ? 697 : pi);
        float m = pool[pi];
        m_ac[base + l] = m;
        msum += m;
        xc[l] = row[l] - m;
    }
    float m_all = blockSum256(msum, red) * (1.f / 722.f);
    __syncthreads();
    for (int i = tid; i < 698; i += 256) {
        float p = 0.f;
        for (int j = 0; j < 25; j++) p += fabsf(xc[i + j]);
        pool[i] = p * (1.f / 25.f);
    }
    __syncthreads();
    float ssum = 0.f;
    for (int l = tid; l < NDWT; l += 256) {
        int pi = l - 12; pi = pi < 0 ? 0 : (pi > 697 ? 697 : pi);
        float sd = pool[pi] + 1e-5f;
        s_ac[base + l] = sd;
        ssum += sd;
        acp[base + l] = xc[l] / sd;
    }
    float s_all = blockSum256(ssum, red) * (1.f / 722.f);
    if (tid == 0) { stat[r] = m_all; stat[RTOT + r] = s_all; }
    __syncthreads();

    // ================= DC =================
    for (int i = tid; i < NDWT; i += 256) row[i] = dc0in[base + i];
    __syncthreads();
    for (int i = tid; i < 698; i += 256) {
        float p = 0.f;
        for (int j = 0; j < 25; j++) p += row[i + j];
        pool[i] = p * (1.f / 25.f);
    }
    __syncthreads();
    float msum2 = 0.f;
    for (int l = tid; l < NDWT; l += 256) {
        int pi = l - 12; pi = pi < 0 ? 0 : (pi > 697 ? 697 : pi);
        float m = pool[pi];
        m_dc[base + l] = m;
        msum2 += m;
        xc[l] = row[l] - m;
    }
    float m_all2 = blockSum256(msum2, red) * (1.f / 722.f);
    __syncthreads();
    for (int i = tid; i < 698; i += 256) {
        float p = 0.f;
        for (int j = 0; j < 25; j++) p += fabsf(xc[i + j]);
        pool[i] = p * (1.f / 25.f);
    }
    __syncthreads();
    float ssum2 = 0.f;
    for (int l = tid; l < NDWT; l += 256) {
        int pi = l - 12; pi = pi < 0 ? 0 : (pi > 697 ? 697 : pi);
        float sd = pool[pi] + 1e-5f;
        s_dc[base + l] = sd;
        ssum2 += sd;
        dcp[base + l] = xc[l] / sd;
    }
    float s_all2 = blockSum256(ssum2, red) * (1.f / 722.f);
    if (tid == 0) { stat[2 * RTOT + r] = m_all2; stat[3 * RTOT + r] = s_all2; }
}

// ---------------- FFT-722 (mixed radix 2 x 19 x 19), forward, in LDS ----------------
// Input complex in X, scratch T, result in OUT. X and T are clobbered.
__device__ void fft722_dev(float2* X, float2* T, float2* OUT, const float2* Wt) {
    const int tid = threadIdx.x;
    // Stage 1: per half p, 19 DFT-19s over j; A[p][r][t]
    for (int q = tid; q < NDWT; q += 256) {
        int p = (q >= 361) ? 1 : 0;
        int rem = q - 361 * p;
        int rr = rem / 19, t = rem - rr * 19;
        float sx = 0.f, sy = 0.f;
        int u = 0;                    // (j*t) mod 19
        int xb = 2 * rr + p;          // x index for j=0: 2*(rr+19j)+p
        for (int j = 0; j < 19; j++) {
            float2 a = X[xb + 38 * j];
            float2 w = Wt[38 * u];    // W19^u
            sx += a.x * w.x - a.y * w.y;
            sy += a.x * w.y + a.y * w.x;
            u += t; if (u >= 19) u -= 19;
        }
        T[q] = make_float2(sx, sy);
    }
    __syncthreads();
    // Stage 2: Y_p[k] = sum_r A[p][r][k%19] * W361^{r*k}
    for (int q = tid; q < NDWT; q += 256) {
        int p = (q >= 361) ? 1 : 0;
        int k = q - 361 * p;
        int t = k % 19;
        float sx = 0.f, sy = 0.f;
        int m = 0, step = 2 * k;      // W361^{rk} = W722^{2rk}
        const float2* Ap = T + p * 361 + t;
        for (int rr = 0; rr < 19; rr++) {
            float2 a = Ap[19 * rr];
            float2 w = Wt[m];
            sx += a.x * w.x - a.y * w.y;
            sy += a.x * w.y + a.y * w.x;
            m += step; if (m >= NDWT) m -= NDWT;
        }
        X[q] = make_float2(sx, sy);
    }
    __syncthreads();
    // Stage 3: radix-2 combine
    for (int k = tid; k < 361; k += 256) {
        float2 e = X[k], o = X[361 + k], w = Wt[k];
        float ox = o.x * w.x - o.y * w.y;
        float oy = o.x * w.y + o.y * w.x;
        OUT[k]       = make_float2(e.x + ox, e.y + oy);
        OUT[361 + k] = make_float2(e.x - ox, e.y - oy);
    }
    __syncthreads();
}

// ---------------- fused: fft(ac_n), fft(dc), top-362 by |acF|, mix, ifft -> dc (in place) ----------------
__global__ __launch_bounds__(256) void fft_mix_kernel(const float* __restrict__ acn,
                                                      float* __restrict__ dcp,
                                                      const float2* __restrict__ Wtab) {
    __shared__ float2 Wt[NDWT];
    __shared__ float2 bufX[NDWT];
    __shared__ float2 bufT[NDWT];
    __shared__ float2 acF[NDWT];
    __shared__ float2 dcF[NDWT];
    __shared__ float smag[1024];
    __shared__ int   sidx[1024];
    __shared__ int   flags[NDWT];
    const int r = blockIdx.x, tid = threadIdx.x;
    const size_t base = (size_t)r * NDWT;

    for (int i = tid; i < NDWT; i += 256) Wt[i] = Wtab[i];
    for (int i = tid; i < NDWT; i += 256) bufX[i] = make_float2(acn[base + i], 0.f);
    __syncthreads();
    fft722_dev(bufX, bufT, acF, Wt);
    for (int i = tid; i < NDWT; i += 256) bufX[i] = make_float2(dcp[base + i], 0.f);
    __syncthreads();
    fft722_dev(bufX, bufT, dcF, Wt);

    for (int i = tid; i < 1024; i += 256) {
        if (i < NDWT) { float2 a = acF[i]; smag[i] = a.x * a.x + a.y * a.y; sidx[i] = i; }
        else          { smag[i] = -1.f; sidx[i] = i; }
    }
    for (int i = tid; i < NDWT; i += 256) flags[i] = 0;
    __syncthreads();

    // bitonic sort (descending mag, ties -> ascending index)
    for (int kk = 2; kk <= 1024; kk <<= 1) {
        for (int j = kk >> 1; j > 0; j >>= 1) {
            for (int i = tid; i < 1024; i += 256) {
                int ij = i ^ j;
                if (ij > i) {
                    float ma = smag[i], mb = smag[ij];
                    int ia = sidx[i], ibx = sidx[ij];
                    bool aFirst = (ma > mb) || (ma == mb && ia < ibx);
                    bool up = ((i & kk) == 0);
                    if (up ? !aFirst : aFirst) {
                        smag[i] = mb; smag[ij] = ma;
                        sidx[i] = ibx; sidx[ij] = ia;
                    }
                }
            }
            __syncthreads();
        }
    }
    for (int s2 = tid; s2 < NFREQ; s2 += 256) flags[sidx[s2]] = 1;
    __syncthreads();
    // mix and conjugate (ifft via forward fft of conj)
    for (int i = tid; i < NDWT; i += 256) {
        float2 d = dcF[i];
        if (flags[i]) { float2 a = acF[i]; d.x = 0.5f * (a.x + d.x); d.y = 0.5f * (a.y + d.y); }
        bufX[i] = make_float2(d.x, -d.y);
    }
    __syncthreads();
    fft722_dev(bufX, bufT, acF, Wt);
    for (int i = tid; i < NDWT; i += 256) dcp[base + i] = acF[i].x * (1.f / 722.f);
}

// ---------------- inverse DWT: (lo,hi) rows of length n -> out rows of length 2n-4 ----------------
__global__ __launch_bounds__(256) void iwt_kernel(const float* __restrict__ lo,
                                                  const float* __restrict__ hi,
                                                  float* __restrict__ out,
                                                  int n, int outlen) {
    const int r = blockIdx.x;
    const int t = blockIdx.y * 256 + threadIdx.x;
    if (t >= outlen) return;
    const float* lp = lo + (size_t)r * n;
    const float* hp = hi + (size_t)r * n;
    float s = 0.f;
    if (t & 1) {
        int j0 = (t - 1) >> 1;
        #pragma unroll
        for (int i = 0; i < 3; i++) s += lp[j0 + i] * c_lo[2 * i] + hp[j0 + i] * c_hi[2 * i];
    } else {
        int j0 = t >> 1;
        #pragma unroll
        for (int i = 0; i < 3; i++) s += lp[j0 + i] * c_lo[2 * i + 1] + hp[j0 + i] * c_hi[2 * i + 1];
    }
    out[(size_t)r * outlen + t] = s;
}

// ---------------- generic fp32 GEMM: C = op(A) @ W^T (+epilogue), W is Nc x K row-major ----------------
// MIN_: 0 plain, 1 subtract per-row ibias from A
// MOUT_: 0 plain, 1 relu, 2 +obias[row], 3 relu(x+obias[row])+1e-5, 4 +cbias[col]
template <int MIN_, int MOUT_>
__global__ __launch_bounds__(256) void gemm_kernel(
    const float* __restrict__ A, int lda,
    const float* __restrict__ W,
    float* __restrict__ Cmat, int ldc,
    int M, int Nc, int K,
    const float* __restrict__ ibias,
    const float* __restrict__ obias,
    const float* __restrict__ cbias) {
    __shared__ float As[16][68];
    __shared__ float Ws[16][68];
    const int bm = blockIdx.x * 64, bn = blockIdx.y * 64;
    const int tid = threadIdx.x;
    const int tm = (tid & 15) * 4, tn = (tid >> 4) * 4;
    const int lr = tid >> 2, lk = (tid & 3) * 4;
    float acc[4][4] = {};
    const float ib = (MIN_ == 1) ? ibias[bm + lr] : 0.f;
    const float* ap = A + (size_t)(bm + lr) * lda;
    const int wn = bn + lr;
    const float* wp = W + (size_t)(wn < Nc ? wn : 0) * K;
    for (int k0 = 0; k0 < K; k0 += 16) {
        #pragma unroll
        for (int q = 0; q < 4; q++) {
            int k = k0 + lk + q;
            As[lk + q][lr] = (k < K) ? (ap[k] - ib) : 0.f;
            Ws[lk + q][lr] = (wn < Nc && k < K) ? wp[k] : 0.f;
        }
        __syncthreads();
        #pragma unroll
        for (int kk = 0; kk < 16; kk++) {
            float a0 = As[kk][tm + 0], a1 = As[kk][tm + 1], a2 = As[kk][tm + 2], a3 = As[kk][tm + 3];
            float b0 = Ws[kk][tn + 0], b1 = Ws[kk][tn + 1], b2 = Ws[kk][tn + 2], b3 = Ws[kk][tn + 3];
            acc[0][0] += a0 * b0; acc[0][1] += a0 * b1; acc[0][2] += a0 * b2; acc[0][3] += a0 * b3;
            acc[1][0] += a1 * b0; acc[1][1] += a1 * b1; acc[1][2] += a1 * b2; acc[1][3] += a1 * b3;
            acc[2][0] += a2 * b0; acc[2][1] += a2 * b1; acc[2][2] += a2 * b2; acc[2][3] += a2 * b3;
            acc[3][0] += a3 * b0; acc[3][1] += a3 * b1; acc[3][2] += a3 * b2; acc[3][3] += a3 * b3;
        }
        __syncthreads();
    }
    #pragma unroll
    for (int i = 0; i < 4; i++) {
        const int gm = bm + tm + i;
        const float ob = (MOUT_ == 2 || MOUT_ == 3) ? obias[gm] : 0.f;
        #pragma unroll
        for (int j = 0; j < 4; j++) {
            const int gn = bn + tn + j;
            if (gn < Nc) {
                float v = acc[i][j];
                if (MOUT_ == 1) v = fmaxf(v, 0.f);
                else if (MOUT_ == 2) v += ob;
                else if (MOUT_ == 3) v = fmaxf(v + ob, 0.f) + 1e-5f;
                else if (MOUT_ == 4) v += cbias[gn];
                Cmat[(size_t)gm * ldc + gn] = v;
            }
        }
    }
}

extern "C" void kernel_launch(void* const* d_in, const int* in_sizes, int n_in,
                              void* d_out, int out_size, void* d_ws, size_t ws_size,
                              hipStream_t stream) {
    const float* x = (const float*)d_in[0];
    const float* latent_w = (const float*)d_in[1];
    // Input order: setup_inputs() dict order puts latent_b LAST (idx 18); be robust
    // to the alternative (reference-arg order) where latent_b is idx 2.
    int p0;
    const float* latent_b;
    if (n_in > 2 && in_sizes[2] == 512) { latent_b = (const float*)d_in[2]; p0 = 3; }
    else                                { latent_b = (const float*)d_in[18]; p0 = 2; }

    float* ws = (float*)d_ws;
    const size_t RN = (size_t)RTOT * NDWT;
    float* ac0  = ws;            // after rowstats: holds ac_n (aliased)
    float* dc0  = ws + RN;
    float* acp  = ws + 2 * RN;   // ac = xc/std
    float* dcp  = ws + 3 * RN;   // dc = xc/std -> overwritten by real(ifft(mixed))
    float* m_ac = ws + 4 * RN;
    float* s_ac = ws + 5 * RN;
    float* m_dc = ws + 6 * RN;
    float* s_dc = ws + 7 * RN;
    float* stat = ws + 8 * RN;                          // 4 * 8192
    float2* Wtab = (float2*)(ws + 8 * RN + 4 * RTOT);   // 722 float2
    float* mlpA = ws + 8 * RN + 4 * RTOT + 2048;        // 8192*1024
    float* mlpB = mlpA + (size_t)RTOT * 1024;           // 8192*512
    float* mlpC = mlpB + (size_t)RTOT * 512;            // 8192*512
    float* heads = mlpC + (size_t)RTOT * 512;           // 4 * 8192*362
    float* xr = mlpA;  // alias: reused AFTER all MLP chains complete (needs 8192*1440 <= A+B)

    wtab_kernel<<<dim3(3), dim3(256), 0, stream>>>(Wtab);
    dwt_kernel<<<dim3(64, 46), dim3(128, 4), 0, stream>>>(x, ac0, dc0);
    rowstats_kernel<<<dim3(RTOT), dim3(256), 0, stream>>>(
        ac0, dc0, ac0, acp, m_ac, s_ac, dcp, m_dc, s_dc, stat);

    const size_t HR = (size_t)RTOT * NHEAD;
    for (int chain = 0; chain < 4; chain++) {
        int branch = chain >> 1, isStd = chain & 1;
        const float* Ain  = branch ? (isStd ? s_dc : m_dc) : (isStd ? s_ac : m_ac);
        const float* bias = stat + (size_t)(branch * 2 + isStd) * RTOT;
        int wb = p0 + branch * 8;
        const float* proj = (const float*)d_in[wb + (isStd ? 1 : 0)];
        const float* w1   = (const float*)d_in[wb + (isStd ? 4 : 2)];
        const float* w2   = (const float*)d_in[wb + (isStd ? 5 : 3)];
        const float* pred = (const float*)d_in[wb + (isStd ? 7 : 6)];
        float* head = heads + (size_t)chain * HR;
        gemm_kernel<1, 0><<<dim3(128, 8), dim3(256), 0, stream>>>(
            Ain, NDWT, proj, mlpB, 512, RTOT, 512, NDWT, bias, nullptr, nullptr);
        gemm_kernel<0, 1><<<dim3(128, 16), dim3(256), 0, stream>>>(
            mlpB, 512, w1, mlpA, 1024, RTOT, 1024, 512, nullptr, nullptr, nullptr);
        gemm_kernel<0, 0><<<dim3(128, 8), dim3(256), 0, stream>>>(
            mlpA, 1024, w2, mlpC, 512, RTOT, 512, 1024, nullptr, nullptr, nullptr);
        if (!isStd)
            gemm_kernel<0, 2><<<dim3(128, 6), dim3(256), 0, stream>>>(
                mlpC, 512, pred, head, NHEAD, RTOT, NHEAD, 512, nullptr, bias, nullptr);
        else
            gemm_kernel<0, 3><<<dim3(128, 6), dim3(256), 0, stream>>>(
                mlpC, 512, pred, head, NHEAD, RTOT, NHEAD, 512, nullptr, bias, nullptr);
    }

    float* out = (float*)d_out;
    float* out_mean = out + (size_t)67108864;           // 64*128*16*512
    float* out_std  = out_mean + (size_t)5898240;       // 64*128*720
    iwt_kernel<<<dim3(RTOT, 3), dim3(256), 0, stream>>>(heads + 0 * HR, heads + 2 * HR, out_mean, NHEAD, 720);
    iwt_kernel<<<dim3(RTOT, 3), dim3(256), 0, stream>>>(heads + 1 * HR, heads + 3 * HR, out_std,  NHEAD, 720);

    fft_mix_kernel<<<dim3(RTOT), dim3(256), 0, stream>>>(ac0, dcp, Wtab);
    iwt_kernel<<<dim3(RTOT, 6), dim3(256), 0, stream>>>(acp, dcp, xr, NDWT, LSEQ);

    // emb = xr(131072 x 90) @ latent_w^T (512 x 90) + latent_b
    gemm_kernel<0, 4><<<dim3(2048, 8), dim3(256), 0, stream>>>(
        xr, 90, latent_w, out, 512, 131072, 512, 90, nullptr, nullptr, latent_b);
}

// Round 2
// 942.761 us; speedup vs baseline: 4.8359x; 4.8359x over previous
//
#include <hip/hip_runtime.h>
#include <cmath>

#define RTOT 8192        // B*C rows
#define NDWT 722         // SEQ_LEN/2+2
#define KP1  736         // NDWT padded to 32
#define LSEQ 1440
#define NHEAD 362        // PRED_LEN/2+2
#define NFREQ 362

typedef __bf16 bf16x8 __attribute__((ext_vector_type(8)));
typedef float f32x4 __attribute__((ext_vector_type(4)));

__device__ __forceinline__ unsigned short f2bf(float f) {
    unsigned u = __float_as_uint(f);
    u += 0x7fffu + ((u >> 16) & 1u);
    return (unsigned short)(u >> 16);
}

__constant__ float c_lo[6] = {0.035226291882100656f, -0.08544127388224149f, -0.13501102001039084f,
                              0.4598775021193313f, 0.8068915093133388f, 0.3326705529509569f};
__constant__ float c_hi[6] = {-0.3326705529509569f, 0.8068915093133388f, -0.4598775021193313f,
                              -0.13501102001039084f, 0.08544127388224149f, 0.035226291882100656f};

// ---------------- twiddle table: W^m = exp(-2*pi*i*m/722) ----------------
__global__ void wtab_kernel(float2* __restrict__ Wtab) {
    int m = blockIdx.x * blockDim.x + threadIdx.x;
    if (m < NDWT) {
        double ang = -2.0 * 3.141592653589793238462643383279502884 * (double)m / (double)NDWT;
        Wtab[m] = make_float2((float)cos(ang), (float)sin(ang));
    }
}

// ---------------- weight fp32 -> bf16 with zero padding ----------------
__global__ __launch_bounds__(256) void cvt_kernel(const float* __restrict__ src, unsigned short* __restrict__ dst,
                                                  int N, int K, int Np, int Kp) {
    int idx = blockIdx.x * 256 + threadIdx.x;
    if (idx >= Np * Kp) return;
    int r = idx / Kp, c = idx - r * Kp;
    float v = (r < N && c < K) ? src[(size_t)r * K + c] : 0.f;
    dst[idx] = f2bf(v);
}

// ---------------- DWT: x (64,1440,128) -> ac0, dc0 (8192,722) ----------------
__global__ __launch_bounds__(512) void dwt_kernel(const float* __restrict__ x,
                                                  float* __restrict__ ac0,
                                                  float* __restrict__ dc0) {
    int b = blockIdx.x;
    int c = threadIdx.x;                       // 0..127
    int t0 = blockIdx.y * 16 + threadIdx.y * 4;
    for (int i = 0; i < 4; i++) {
        int t = t0 + i;
        if (t >= NDWT) break;
        float slo = 0.f, shi = 0.f;
        #pragma unroll
        for (int j = 0; j < 6; j++) {
            int l = 2 * t + 1 - j;
            float v = (l >= 0 && l < LSEQ) ? x[((size_t)b * LSEQ + l) * 128 + c] : 0.f;
            slo += v * c_lo[j];
            shi += v * c_hi[j];
        }
        size_t o = ((size_t)b * 128 + c) * NDWT + t;
        ac0[o] = slo;
        dc0[o] = shi;
    }
}

__device__ __forceinline__ float blockSum256(float v, float* red) {
    #pragma unroll
    for (int o = 32; o > 0; o >>= 1) v += __shfl_down(v, o, 64);
    int lane = threadIdx.x & 63, wid = threadIdx.x >> 6;
    __syncthreads();
    if (lane == 0) red[wid] = v;
    __syncthreads();
    return red[0] + red[1] + red[2] + red[3];
}

// ---------------- per-row stats: inst_norm, mov_norm x2, centered bf16 outputs ----------------
__global__ __launch_bounds__(256) void rowstats_kernel(
    const float* __restrict__ ac0in, const float* __restrict__ dc0in,
    float* __restrict__ acn,   // aliases ac0in
    float* __restrict__ acp,
    float* __restrict__ dcp,   // aliases dc0in
    unsigned short* __restrict__ mcac, unsigned short* __restrict__ scac,
    unsigned short* __restrict__ mcdc, unsigned short* __restrict__ scdc,
    float* __restrict__ stat /* [4][8192] */) {
    __shared__ float row[NDWT];
    __shared__ float xc[NDWT];
    __shared__ float pool[698];
    __shared__ float red[4];
    const int r = blockIdx.x, tid = threadIdx.x;
    const size_t base = (size_t)r * NDWT;
    const size_t baseP = (size_t)r * KP1;

    // ================= AC =================
    for (int i = tid; i < NDWT; i += 256) row[i] = ac0in[base + i];
    __syncthreads();
    float s = 0.f;
    for (int i = tid; i < NDWT; i += 256) s += row[i];
    float mean = blockSum256(s, red) * (1.f / 722.f);
    s = 0.f;
    for (int i = tid; i < NDWT; i += 256) s += row[i] - mean;
    float m2 = blockSum256(s, red) * (1.f / 722.f);
    s = 0.f;
    for (int i = tid; i < NDWT; i += 256) { float d = row[i] - mean - m2; s += d * d; }
    float var = blockSum256(s, red) * (1.f / 722.f);
    float inv = 1.f / sqrtf(var + 1e-5f);
    for (int i = tid; i < NDWT; i += 256) acn[base + i] = (row[i] - mean) * inv;

    for (int i = tid; i < 698; i += 256) {
        float p = 0.f;
        for (int j = 0; j < 25; j++) p += row[i + j];
        pool[i] = p * (1.f / 25.f);
    }
    __syncthreads();
    float msum = 0.f;
    for (int l = tid; l < NDWT; l += 256) {
        int pi = l - 12; pi = pi < 0 ? 0 : (pi > 697 ? 697 : pi);
        float m = pool[pi];
        msum += m;
        xc[l] = row[l] - m;
    }
    float m_all = blockSum256(msum, red) * (1.f / 722.f);
    __syncthreads();
    for (int i = tid; i < 698; i += 256) {
        float p = 0.f;
        for (int j = 0; j < 25; j++) p += fabsf(xc[i + j]);
        pool[i] = p * (1.f / 25.f);
    }
    __syncthreads();
    float ssum = 0.f;
    for (int l = tid; l < NDWT; l += 256) {
        int pi = l - 12; pi = pi < 0 ? 0 : (pi > 697 ? 697 : pi);
        float sd = pool[pi] + 1e-5f;
        ssum += sd;
        acp[base + l] = xc[l] / sd;
    }
    float s_all = blockSum256(ssum, red) * (1.f / 722.f);
    if (tid == 0) { stat[r] = m_all; stat[RTOT + r] = s_all; }
    // centered bf16 (row[], xc[], pool[] all still valid here)
    for (int l = tid; l < KP1; l += 256) {
        if (l < NDWT) {
            float m = row[l] - xc[l];
            int pi = l - 12; pi = pi < 0 ? 0 : (pi > 697 ? 697 : pi);
            float sd = pool[pi] + 1e-5f;
            mcac[baseP + l] = f2bf(m - m_all);
            scac[baseP + l] = f2bf(sd - s_all);
        } else { mcac[baseP + l] = 0; scac[baseP + l] = 0; }
    }
    __syncthreads();

    // ================= DC =================
    for (int i = tid; i < NDWT; i += 256) row[i] = dc0in[base + i];
    __syncthreads();
    for (int i = tid; i < 698; i += 256) {
        float p = 0.f;
        for (int j = 0; j < 25; j++) p += row[i + j];
        pool[i] = p * (1.f / 25.f);
    }
    __syncthreads();
    float msum2 = 0.f;
    for (int l = tid; l < NDWT; l += 256) {
        int pi = l - 12; pi = pi < 0 ? 0 : (pi > 697 ? 697 : pi);
        float m = pool[pi];
        msum2 += m;
        xc[l] = row[l] - m;
    }
    float m_all2 = blockSum256(msum2, red) * (1.f / 722.f);
    __syncthreads();
    for (int i = tid; i < 698; i += 256) {
        float p = 0.f;
        for (int j = 0; j < 25; j++) p += fabsf(xc[i + j]);
        pool[i] = p * (1.f / 25.f);
    }
    __syncthreads();
    float ssum2 = 0.f;
    for (int l = tid; l < NDWT; l += 256) {
        int pi = l - 12; pi = pi < 0 ? 0 : (pi > 697 ? 697 : pi);
        float sd = pool[pi] + 1e-5f;
        ssum2 += sd;
        dcp[base + l] = xc[l] / sd;
    }
    float s_all2 = blockSum256(ssum2, red) * (1.f / 722.f);
    if (tid == 0) { stat[2 * RTOT + r] = m_all2; stat[3 * RTOT + r] = s_all2; }
    for (int l = tid; l < KP1; l += 256) {
        if (l < NDWT) {
            float m = row[l] - xc[l];
            int pi = l - 12; pi = pi < 0 ? 0 : (pi > 697 ? 697 : pi);
            float sd = pool[pi] + 1e-5f;
            mcdc[baseP + l] = f2bf(m - m_all2);
            scdc[baseP + l] = f2bf(sd - s_all2);
        } else { mcdc[baseP + l] = 0; scdc[baseP + l] = 0; }
    }
}

// ---------------- FFT-722 (mixed radix 2 x 19 x 19), forward, in LDS ----------------
__device__ void fft722_dev(float2* X, float2* T, float2* OUT, const float2* Wt) {
    const int tid = threadIdx.x;
    for (int q = tid; q < NDWT; q += 256) {
        int p = (q >= 361) ? 1 : 0;
        int rem = q - 361 * p;
        int rr = rem / 19, t = rem - rr * 19;
        float sx = 0.f, sy = 0.f;
        int u = 0;
        int xb = 2 * rr + p;
        for (int j = 0; j < 19; j++) {
            float2 a = X[xb + 38 * j];
            float2 w = Wt[38 * u];
            sx += a.x * w.x - a.y * w.y;
            sy += a.x * w.y + a.y * w.x;
            u += t; if (u >= 19) u -= 19;
        }
        T[q] = make_float2(sx, sy);
    }
    __syncthreads();
    for (int q = tid; q < NDWT; q += 256) {
        int p = (q >= 361) ? 1 : 0;
        int k = q - 361 * p;
        int t = k % 19;
        float sx = 0.f, sy = 0.f;
        int m = 0, step = 2 * k;
        const float2* Ap = T + p * 361 + t;
        for (int rr = 0; rr < 19; rr++) {
            float2 a = Ap[19 * rr];
            float2 w = Wt[m];
            sx += a.x * w.x - a.y * w.y;
            sy += a.x * w.y + a.y * w.x;
            m += step; if (m >= NDWT) m -= NDWT;
        }
        X[q] = make_float2(sx, sy);
    }
    __syncthreads();
    for (int k = tid; k < 361; k += 256) {
        float2 e = X[k], o = X[361 + k], w = Wt[k];
        float ox = o.x * w.x - o.y * w.y;
        float oy = o.x * w.y + o.y * w.x;
        OUT[k]       = make_float2(e.x + ox, e.y + oy);
        OUT[361 + k] = make_float2(e.x - ox, e.y - oy);
    }
    __syncthreads();
}

// ---------------- fused: packed FFT(acn + i*dc), radix-select top-362, mix, ifft ----------------
__global__ __launch_bounds__(256) void fft_mix_kernel(const float* __restrict__ acn,
                                                      float* __restrict__ dcp,
                                                      const float2* __restrict__ Wtab) {
    __shared__ float2 Wt[NDWT];
    __shared__ float2 B1[NDWT];
    __shared__ float2 B2[NDWT];
    __shared__ float2 B3[NDWT];
    __shared__ float smag[NDWT];
    __shared__ int   flags[NDWT];
    __shared__ unsigned hist[256];
    __shared__ unsigned suf[256];
    __shared__ int excl[256];
    __shared__ unsigned sh_digit, sh_rem;
    const int r = blockIdx.x, tid = threadIdx.x;
    const size_t base = (size_t)r * NDWT;

    for (int i = tid; i < NDWT; i += 256) Wt[i] = Wtab[i];
    // pack two real FFTs into one complex FFT
    for (int i = tid; i < NDWT; i += 256) B1[i] = make_float2(acn[base + i], dcp[base + i]);
    __syncthreads();
    fft722_dev(B1, B2, B3, Wt);           // Z in B3
    // unpack: acF -> B1, dcF -> B2
    for (int k = tid; k < 362; k += 256) {
        int m = (NDWT - k) % NDWT;
        float2 zk = B3[k], zm = B3[m];
        float2 ak = make_float2(0.5f * (zk.x + zm.x), 0.5f * (zk.y - zm.y));
        float2 dk = make_float2(0.5f * (zk.y + zm.y), 0.5f * (zm.x - zk.x));
        B1[k] = ak; B2[k] = dk;
        smag[k] = ak.x * ak.x + ak.y * ak.y;
        if (m != k) {
            float2 am = make_float2(0.5f * (zm.x + zk.x), 0.5f * (zm.y - zk.y));
            float2 dm = make_float2(0.5f * (zm.y + zk.y), 0.5f * (zk.x - zm.x));
            B1[m] = am; B2[m] = dm;
            smag[m] = am.x * am.x + am.y * am.y;
        }
    }
    __syncthreads();

    // ---- radix-select: pivot = 362nd largest mag^2 (bits monotone for non-neg floats) ----
    unsigned prefix = 0, rem = NFREQ;
    for (int shift = 24; shift >= 0; shift -= 8) {
        hist[tid] = 0;
        __syncthreads();
        unsigned hm = (shift == 24) ? 0u : (0xFFFFFFFFu << (shift + 8));
        for (int i = tid; i < NDWT; i += 256) {
            unsigned b = __float_as_uint(smag[i]);
            if ((b & hm) == prefix) atomicAdd(&hist[(b >> shift) & 255], 1u);
        }
        __syncthreads();
        suf[tid] = hist[tid];
        __syncthreads();
        for (int off = 1; off < 256; off <<= 1) {
            unsigned v = (tid + off < 256) ? suf[tid + off] : 0;
            __syncthreads();
            suf[tid] += v;
            __syncthreads();
        }
        unsigned Shere = suf[tid];
        unsigned Snext = (tid < 255) ? suf[tid + 1] : 0;
        if (Shere >= rem && Snext < rem) { sh_digit = (unsigned)tid; sh_rem = rem - Snext; }
        __syncthreads();
        prefix |= (sh_digit << shift);
        rem = sh_rem;
        __syncthreads();
    }
    // flags: strictly greater, plus `rem` lowest-index equals
    for (int i = tid; i < NDWT; i += 256)
        flags[i] = (__float_as_uint(smag[i]) > prefix) ? 1 : 0;
    int c0 = tid * 3, cnt = 0;
    #pragma unroll
    for (int j = 0; j < 3; j++) {
        int i = c0 + j;
        if (i < NDWT && __float_as_uint(smag[i]) == prefix) cnt++;
    }
    excl[tid] = cnt;
    __syncthreads();
    for (int off = 1; off < 256; off <<= 1) {
        int v = (tid >= off) ? excl[tid - off] : 0;
        __syncthreads();
        excl[tid] += v;
        __syncthreads();
    }
    int myexc = excl[tid] - cnt, o = 0;
    #pragma unroll
    for (int j = 0; j < 3; j++) {
        int i = c0 + j;
        if (i < NDWT && __float_as_uint(smag[i]) == prefix) {
            if (myexc + o < (int)rem) flags[i] = 1;
            o++;
        }
    }
    __syncthreads();

    // mix and conjugate (ifft via forward fft of conj)
    for (int i = tid; i < NDWT; i += 256) {
        float2 d = B2[i];
        if (flags[i]) { float2 a = B1[i]; d.x = 0.5f * (a.x + d.x); d.y = 0.5f * (a.y + d.y); }
        B3[i] = make_float2(d.x, -d.y);
    }
    __syncthreads();
    fft722_dev(B3, B1, B2, Wt);
    for (int i = tid; i < NDWT; i += 256) dcp[base + i] = B2[i].x * (1.f / 722.f);
}

// ---------------- inverse DWT (fp32 out) for mean/std ----------------
__global__ __launch_bounds__(256) void iwt_kernel(const float* __restrict__ lo,
                                                  const float* __restrict__ hi,
                                                  float* __restrict__ out,
                                                  int n, int outlen) {
    const int r = blockIdx.x;
    const int t = blockIdx.y * 256 + threadIdx.x;
    if (t >= outlen) return;
    const float* lp = lo + (size_t)r * n;
    const float* hp = hi + (size_t)r * n;
    float s = 0.f;
    if (t & 1) {
        int j0 = (t - 1) >> 1;
        #pragma unroll
        for (int i = 0; i < 3; i++) s += lp[j0 + i] * c_lo[2 * i] + hp[j0 + i] * c_hi[2 * i];
    } else {
        int j0 = t >> 1;
        #pragma unroll
        for (int i = 0; i < 3; i++) s += lp[j0 + i] * c_lo[2 * i + 1] + hp[j0 + i] * c_hi[2 * i + 1];
    }
    out[(size_t)r * outlen + t] = s;
}

// ---------------- inverse DWT -> xr, written bf16 reshaped (131072 x 96, cols 90..95 zero) ----------------
__global__ __launch_bounds__(256) void iwt_xr_kernel(const float* __restrict__ lo,
                                                     const float* __restrict__ hi,
                                                     unsigned short* __restrict__ xrbf) {
    const int r = blockIdx.x;
    const int t = blockIdx.y * 256 + threadIdx.x;
    if (blockIdx.y == 0 && threadIdx.x < 96) {
        int sub = threadIdx.x / 6, c = 90 + threadIdx.x % 6;
        xrbf[((size_t)r * 16 + sub) * 96 + c] = 0;
    }
    if (t >= LSEQ) return;
    const float* lp = lo + (size_t)r * NDWT;
    const float* hp = hi + (size_t)r * NDWT;
    float s = 0.f;
    if (t & 1) {
        int j0 = (t - 1) >> 1;
        #pragma unroll
        for (int i = 0; i < 3; i++) s += lp[j0 + i] * c_lo[2 * i] + hp[j0 + i] * c_hi[2 * i];
    } else {
        int j0 = t >> 1;
        #pragma unroll
        for (int i = 0; i < 3; i++) s += lp[j0 + i] * c_lo[2 * i + 1] + hp[j0 + i] * c_hi[2 * i + 1];
    }
    xrbf[((size_t)r * 16 + t / 90) * 96 + (t % 90)] = f2bf(s);
}

// ---------------- bf16 MFMA GEMM: C = A @ W^T, 128x128 tile, BK=32 (m97 structure) ----------------
// A: M x lda bf16 (K zero-padded), W: (>=gridDim.y*128) x ldw bf16 (K zero-padded)
// EPI: 0 bf16 plain, 1 bf16 relu, 2 f32 +obias[row], 3 f32 relu(x+obias[row])+1e-5, 4 f32 +cbias[col]
template <int EPI>
__global__ __launch_bounds__(256) void mfma_gemm(
    const unsigned short* __restrict__ A, int lda,
    const unsigned short* __restrict__ W, int ldw,
    void* __restrict__ Cout, int ldc, int Nc,
    const float* __restrict__ obias, const float* __restrict__ cbias,
    int Ksteps) {
    __shared__ unsigned short As[128 * 32];
    __shared__ unsigned short Bs[128 * 32];
    const int tid = threadIdx.x;
    const int lane = tid & 63, wid = tid >> 6;
    const int bm = blockIdx.x * 128, bn = blockIdx.y * 128;
    const int wr = (wid >> 1) * 64, wc = (wid & 1) * 64;
    f32x4 acc[4][4] = {};
    const int srow = (lane >> 2);             // row within 16-row chunk
    const int scol = (lane & 3) * 8;          // bf16 col offset within 32

    for (int ks = 0; ks < Ksteps; ks++) {
        const int k0 = ks * 32;
        #pragma unroll
        for (int c = 0; c < 2; c++) {
            const int chunk = wid * 2 + c;
            const int row = chunk * 16 + srow;
            const unsigned short* ga = A + (size_t)(bm + row) * lda + k0 + scol;
            const unsigned short* gb = W + (size_t)(bn + row) * ldw + k0 + scol;
            __builtin_amdgcn_global_load_lds(
                (const __attribute__((address_space(1))) unsigned int*)ga,
                (__attribute__((address_space(3))) unsigned int*)(As + chunk * 512), 16, 0, 0);
            __builtin_amdgcn_global_load_lds(
                (const __attribute__((address_space(1))) unsigned int*)gb,
                (__attribute__((address_space(3))) unsigned int*)(Bs + chunk * 512), 16, 0, 0);
        }
        __syncthreads();
        bf16x8 af[4], bfr[4];
        const int kof = (lane >> 4) * 8;
        #pragma unroll
        for (int m = 0; m < 4; m++)
            af[m] = *reinterpret_cast<const bf16x8*>(&As[(wr + m * 16 + (lane & 15)) * 32 + kof]);
        #pragma unroll
        for (int n = 0; n < 4; n++)
            bfr[n] = *reinterpret_cast<const bf16x8*>(&Bs[(wc + n * 16 + (lane & 15)) * 32 + kof]);
        #pragma unroll
        for (int m = 0; m < 4; m++)
            #pragma unroll
            for (int n = 0; n < 4; n++)
                acc[m][n] = __builtin_amdgcn_mfma_f32_16x16x32_bf16(af[m], bfr[n], acc[m][n], 0, 0, 0);
        __syncthreads();
    }

    const int crow0 = bm + wr + (lane >> 4) * 4;
    const int ccol0 = bn + wc + (lane & 15);
    #pragma unroll
    for (int m = 0; m < 4; m++) {
        #pragma unroll
        for (int n = 0; n < 4; n++) {
            const int col = ccol0 + n * 16;
            if (col < Nc) {
                #pragma unroll
                for (int q = 0; q < 4; q++) {
                    const int row = crow0 + m * 16 + q;
                    float v = acc[m][n][q];
                    if (EPI == 0) {
                        ((unsigned short*)Cout)[(size_t)row * ldc + col] = f2bf(v);
                    } else if (EPI == 1) {
                        ((unsigned short*)Cout)[(size_t)row * ldc + col] = f2bf(fmaxf(v, 0.f));
                    } else if (EPI == 2) {
                        ((float*)Cout)[(size_t)row * ldc + col] = v + obias[row];
                    } else if (EPI == 3) {
                        ((float*)Cout)[(size_t)row * ldc + col] = fmaxf(v + obias[row], 0.f) + 1e-5f;
                    } else {
                        ((float*)Cout)[(size_t)row * ldc + col] = v + cbias[col];
                    }
                }
            }
        }
    }
}

extern "C" void kernel_launch(void* const* d_in, const int* in_sizes, int n_in,
                              void* d_out, int out_size, void* d_ws, size_t ws_size,
                              hipStream_t stream) {
    const float* x = (const float*)d_in[0];
    const float* latent_w = (const float*)d_in[1];
    int p0;
    const float* latent_b;
    if (n_in > 2 && in_sizes[2] == 512) { latent_b = (const float*)d_in[2]; p0 = 3; }
    else                                { latent_b = (const float*)d_in[18]; p0 = 2; }

    // ---------------- workspace layout ----------------
    char* wp = (char*)d_ws;
    auto alloc = [&](size_t bytes) { char* p = wp; wp += (bytes + 255) & ~(size_t)255; return p; };
    const size_t RN = (size_t)RTOT * NDWT;
    float* acn  = (float*)alloc(RN * 4);          // dwt ac0 -> inst-normed (alias)
    float* dcb  = (float*)alloc(RN * 4);          // dwt dc0 -> mov-normed dc -> ifft result (alias)
    float* acp  = (float*)alloc(RN * 4);          // mov-normed ac
    float* stat = (float*)alloc(4 * RTOT * 4);
    float2* Wtab = (float2*)alloc(NDWT * 8);
    unsigned short* mcac = (unsigned short*)alloc((size_t)RTOT * KP1 * 2);
    unsigned short* scac = (unsigned short*)alloc((size_t)RTOT * KP1 * 2);
    unsigned short* mcdc = (unsigned short*)alloc((size_t)RTOT * KP1 * 2);
    unsigned short* scdc = (unsigned short*)alloc((size_t)RTOT * KP1 * 2);
    unsigned short* mlpA = (unsigned short*)alloc((size_t)RTOT * 1024 * 2);
    unsigned short* mlpB = (unsigned short*)alloc((size_t)RTOT * 512 * 2);
    unsigned short* mlpC = (unsigned short*)alloc((size_t)RTOT * 512 * 2);
    float* heads = (float*)alloc((size_t)4 * RTOT * NHEAD * 4);
    unsigned short* xrbf = (unsigned short*)alloc((size_t)131072 * 96 * 2);
    unsigned short* wbf[2][4];   // [branch][proj_m, proj_s, w1_m, w2_m] ... enumerated below
    unsigned short* projb[2][2], *w1b[2][2], *w2b[2][2], *predb[2][2];
    for (int b = 0; b < 2; b++) {
        projb[b][0] = (unsigned short*)alloc((size_t)512 * KP1 * 2);
        projb[b][1] = (unsigned short*)alloc((size_t)512 * KP1 * 2);
        w1b[b][0]   = (unsigned short*)alloc((size_t)1024 * 512 * 2);
        w1b[b][1]   = (unsigned short*)alloc((size_t)1024 * 512 * 2);
        w2b[b][0]   = (unsigned short*)alloc((size_t)512 * 1024 * 2);
        w2b[b][1]   = (unsigned short*)alloc((size_t)512 * 1024 * 2);
        predb[b][0] = (unsigned short*)alloc((size_t)384 * 512 * 2);
        predb[b][1] = (unsigned short*)alloc((size_t)384 * 512 * 2);
    }
    unsigned short* latwb = (unsigned short*)alloc((size_t)512 * 96 * 2);
    (void)wbf; (void)ws_size;

    auto cv = [&](const float* s, unsigned short* d, int N, int K, int Np, int Kp) {
        int tot = Np * Kp;
        cvt_kernel<<<dim3((tot + 255) / 256), dim3(256), 0, stream>>>(s, d, N, K, Np, Kp);
    };
    for (int b = 0; b < 2; b++) {
        int wb = p0 + b * 8;
        cv((const float*)d_in[wb + 0], projb[b][0], 512, NDWT, 512, KP1);
        cv((const float*)d_in[wb + 1], projb[b][1], 512, NDWT, 512, KP1);
        cv((const float*)d_in[wb + 2], w1b[b][0], 1024, 512, 1024, 512);
        cv((const float*)d_in[wb + 4], w1b[b][1], 1024, 512, 1024, 512);
        cv((const float*)d_in[wb + 3], w2b[b][0], 512, 1024, 512, 1024);
        cv((const float*)d_in[wb + 5], w2b[b][1], 512, 1024, 512, 1024);
        cv((const float*)d_in[wb + 6], predb[b][0], NHEAD, 512, 384, 512);
        cv((const float*)d_in[wb + 7], predb[b][1], NHEAD, 512, 384, 512);
    }
    cv(latent_w, latwb, 512, 90, 512, 96);

    wtab_kernel<<<dim3(3), dim3(256), 0, stream>>>(Wtab);
    dwt_kernel<<<dim3(64, 46), dim3(128, 4), 0, stream>>>(x, acn, dcb);
    rowstats_kernel<<<dim3(RTOT), dim3(256), 0, stream>>>(
        acn, dcb, acn, acp, dcb, mcac, scac, mcdc, scdc, stat);

    const size_t HR = (size_t)RTOT * NHEAD;
    unsigned short* centered[4] = {mcac, scac, mcdc, scdc};
    for (int chain = 0; chain < 4; chain++) {
        int branch = chain >> 1, isStd = chain & 1;
        const float* bias = stat + (size_t)(branch * 2 + isStd) * RTOT;
        float* head = heads + (size_t)chain * HR;
        mfma_gemm<0><<<dim3(64, 4), dim3(256), 0, stream>>>(
            centered[chain], KP1, projb[branch][isStd], KP1, mlpB, 512, 512, nullptr, nullptr, KP1 / 32);
        mfma_gemm<1><<<dim3(64, 8), dim3(256), 0, stream>>>(
            mlpB, 512, w1b[branch][isStd], 512, mlpA, 1024, 1024, nullptr, nullptr, 16);
        mfma_gemm<0><<<dim3(64, 4), dim3(256), 0, stream>>>(
            mlpA, 1024, w2b[branch][isStd], 1024, mlpC, 512, 512, nullptr, nullptr, 32);
        if (!isStd)
            mfma_gemm<2><<<dim3(64, 3), dim3(256), 0, stream>>>(
                mlpC, 512, predb[branch][isStd], 512, head, NHEAD, NHEAD, bias, nullptr, 16);
        else
            mfma_gemm<3><<<dim3(64, 3), dim3(256), 0, stream>>>(
                mlpC, 512, predb[branch][isStd], 512, head, NHEAD, NHEAD, bias, nullptr, 16);
    }

    float* out = (float*)d_out;
    float* out_mean = out + (size_t)67108864;           // 64*128*16*512
    float* out_std  = out_mean + (size_t)5898240;       // 64*128*720
    iwt_kernel<<<dim3(RTOT, 3), dim3(256), 0, stream>>>(heads + 0 * HR, heads + 2 * HR, out_mean, NHEAD, 720);
    iwt_kernel<<<dim3(RTOT, 3), dim3(256), 0, stream>>>(heads + 1 * HR, heads + 3 * HR, out_std,  NHEAD, 720);

    fft_mix_kernel<<<dim3(RTOT), dim3(256), 0, stream>>>(acn, dcb, Wtab);
    iwt_xr_kernel<<<dim3(RTOT, 6), dim3(256), 0, stream>>>(acp, dcb, xrbf);

    // emb = xr(131072 x 90) @ latent_w^T (512 x 90) + latent_b
    mfma_gemm<4><<<dim3(1024, 4), dim3(256), 0, stream>>>(
        xrbf, 96, latwb, 96, out, 512, 512, nullptr, latent_b, 3);
}

// Round 3
// 672.370 us; speedup vs baseline: 6.7807x; 1.4021x over previous
//
#include <hip/hip_runtime.h>
#include <cmath>

#define RTOT 8192        // B*C rows
#define NDWT 722         // SEQ_LEN/2+2
#define KP1  736         // NDWT padded to 32
#define LSEQ 1440
#define NHEAD 362        // PRED_LEN/2+2
#define NFREQ 362

typedef __bf16 bf16x8 __attribute__((ext_vector_type(8)));
typedef float f32x4 __attribute__((ext_vector_type(4)));
typedef float f32x2 __attribute__((ext_vector_type(2)));

__device__ __forceinline__ unsigned short f2bf(float f) {
    unsigned u = __float_as_uint(f);
    u += 0x7fffu + ((u >> 16) & 1u);
    return (unsigned short)(u >> 16);
}

// complex MAC: s += a*w  (2x v_pk_fma_f32 via op_sel)
__device__ __forceinline__ void cmac(f32x2& s, f32x2 a, f32x2 w) {
    asm("v_pk_fma_f32 %0, %1, %2, %0 op_sel:[0,0,0] op_sel_hi:[0,1,1]\n\t"
        "v_pk_fma_f32 %0, %1, %2, %0 op_sel:[1,1,0] op_sel_hi:[1,0,1] neg_lo:[0,1,0]"
        : "+v"(s) : "v"(a), "v"(w));
}
// complex mul: r = a*b (v_pk_mul + v_pk_fma)
__device__ __forceinline__ f32x2 cmul(f32x2 a, f32x2 b) {
    f32x2 r;
    asm("v_pk_mul_f32 %0, %1, %2 op_sel:[0,0] op_sel_hi:[0,1]\n\t"
        "v_pk_fma_f32 %0, %1, %2, %0 op_sel:[1,1,0] op_sel_hi:[1,0,1] neg_lo:[0,1,0]"
        : "=&v"(r) : "v"(a), "v"(b));
    return r;
}

__constant__ float c_lo[6] = {0.035226291882100656f, -0.08544127388224149f, -0.13501102001039084f,
                              0.4598775021193313f, 0.8068915093133388f, 0.3326705529509569f};
__constant__ float c_hi[6] = {-0.3326705529509569f, 0.8068915093133388f, -0.4598775021193313f,
                              -0.13501102001039084f, 0.08544127388224149f, 0.035226291882100656f};

// ---------------- twiddle table: W^m = exp(-2*pi*i*m/722) ----------------
__global__ void wtab_kernel(float2* __restrict__ Wtab) {
    int m = blockIdx.x * blockDim.x + threadIdx.x;
    if (m < NDWT) {
        double ang = -2.0 * 3.141592653589793238462643383279502884 * (double)m / (double)NDWT;
        Wtab[m] = make_float2((float)cos(ang), (float)sin(ang));
    }
}

// ---------------- batched weight fp32 -> bf16 with zero padding (one dispatch) ----------------
struct CvtDesc { const float* src; unsigned short* dst; int N, K, Np, Kp; };
struct CvtArgs { CvtDesc d[17]; };
__global__ __launch_bounds__(256) void cvt_all_kernel(CvtArgs a) {
    CvtDesc d = a.d[blockIdx.y];
    int idx = blockIdx.x * 256 + threadIdx.x;
    int tot = d.Np * d.Kp;
    if (idx >= tot) return;
    int r = idx / d.Kp, c = idx - r * d.Kp;
    float v = (r < d.N && c < d.K) ? d.src[(size_t)r * d.K + c] : 0.f;
    d.dst[idx] = f2bf(v);
}

// ---------------- DWT: x (64,1440,128) -> ac0, dc0 (8192,722) ----------------
__global__ __launch_bounds__(512) void dwt_kernel(const float* __restrict__ x,
                                                  float* __restrict__ ac0,
                                                  float* __restrict__ dc0) {
    int b = blockIdx.x;
    int c = threadIdx.x;                       // 0..127
    int t0 = blockIdx.y * 16 + threadIdx.y * 4;
    for (int i = 0; i < 4; i++) {
        int t = t0 + i;
        if (t >= NDWT) break;
        float slo = 0.f, shi = 0.f;
        #pragma unroll
        for (int j = 0; j < 6; j++) {
            int l = 2 * t + 1 - j;
            float v = (l >= 0 && l < LSEQ) ? x[((size_t)b * LSEQ + l) * 128 + c] : 0.f;
            slo += v * c_lo[j];
            shi += v * c_hi[j];
        }
        size_t o = ((size_t)b * 128 + c) * NDWT + t;
        ac0[o] = slo;
        dc0[o] = shi;
    }
}

__device__ __forceinline__ float blockSum256(float v, float* red) {
    #pragma unroll
    for (int o = 32; o > 0; o >>= 1) v += __shfl_down(v, o, 64);
    int lane = threadIdx.x & 63, wid = threadIdx.x >> 6;
    __syncthreads();
    if (lane == 0) red[wid] = v;
    __syncthreads();
    return red[0] + red[1] + red[2] + red[3];
}

// sliding-window 25-tap mean over rowv[0..721] -> pool[0..697]; 3 outputs/thread
template <bool ABS>
__device__ __forceinline__ void pool25(const float* rowv, float* pool, int tid) {
    int i0 = tid * 3;
    if (i0 < 698) {
        float s25 = 0.f;
        #pragma unroll
        for (int j = 0; j < 25; j++) { float v = rowv[i0 + j]; s25 += ABS ? fabsf(v) : v; }
        pool[i0] = s25 * (1.f / 25.f);
        #pragma unroll
        for (int qq = 1; qq < 3; qq++) {
            int i = i0 + qq;
            if (i < 698) {
                float vin = rowv[i + 24], vout = rowv[i - 1];
                s25 += (ABS ? fabsf(vin) : vin) - (ABS ? fabsf(vout) : vout);
                pool[i] = s25 * (1.f / 25.f);
            }
        }
    }
}

// ---------------- per-row stats: inst_norm, mov_norm x2, centered bf16 outputs ----------------
__global__ __launch_bounds__(256) void rowstats_kernel(
    const float* __restrict__ ac0in, const float* __restrict__ dc0in,
    float* __restrict__ acn,   // aliases ac0in
    float* __restrict__ acp,
    float* __restrict__ dcp,   // aliases dc0in
    unsigned short* __restrict__ cent,  // [4][RTOT][KP1]: mcac, scac, mcdc, scdc
    float* __restrict__ stat /* [4][8192] */) {
    __shared__ float row[NDWT];
    __shared__ float xc[NDWT];
    __shared__ float pool[698];
    __shared__ float red[4];
    const int r = blockIdx.x, tid = threadIdx.x;
    const size_t base = (size_t)r * NDWT;
    const size_t baseP = (size_t)r * KP1;
    const size_t CS = (size_t)RTOT * KP1;

    // ================= AC =================
    for (int i = tid; i < NDWT; i += 256) row[i] = ac0in[base + i];
    __syncthreads();
    float s = 0.f;
    for (int i = tid; i < NDWT; i += 256) s += row[i];
    float mean = blockSum256(s, red) * (1.f / 722.f);
    s = 0.f;
    for (int i = tid; i < NDWT; i += 256) s += row[i] - mean;
    float m2 = blockSum256(s, red) * (1.f / 722.f);
    s = 0.f;
    for (int i = tid; i < NDWT; i += 256) { float d = row[i] - mean - m2; s += d * d; }
    float var = blockSum256(s, red) * (1.f / 722.f);
    float inv = 1.f / sqrtf(var + 1e-5f);
    for (int i = tid; i < NDWT; i += 256) acn[base + i] = (row[i] - mean) * inv;

    pool25<false>(row, pool, tid);
    __syncthreads();
    float msum = 0.f;
    for (int l = tid; l < NDWT; l += 256) {
        int pi = l - 12; pi = pi < 0 ? 0 : (pi > 697 ? 697 : pi);
        float m = pool[pi];
        msum += m;
        xc[l] = row[l] - m;
    }
    float m_all = blockSum256(msum, red) * (1.f / 722.f);
    __syncthreads();
    pool25<true>(xc, pool, tid);
    __syncthreads();
    float ssum = 0.f;
    for (int l = tid; l < NDWT; l += 256) {
        int pi = l - 12; pi = pi < 0 ? 0 : (pi > 697 ? 697 : pi);
        float sd = pool[pi] + 1e-5f;
        ssum += sd;
        acp[base + l] = xc[l] / sd;
    }
    float s_all = blockSum256(ssum, red) * (1.f / 722.f);
    if (tid == 0) { stat[r] = m_all; stat[RTOT + r] = s_all; }
    for (int l = tid; l < KP1; l += 256) {
        if (l < NDWT) {
            float m = row[l] - xc[l];
            int pi = l - 12; pi = pi < 0 ? 0 : (pi > 697 ? 697 : pi);
            float sd = pool[pi] + 1e-5f;
            cent[baseP + l]      = f2bf(m - m_all);
            cent[CS + baseP + l] = f2bf(sd - s_all);
        } else { cent[baseP + l] = 0; cent[CS + baseP + l] = 0; }
    }
    __syncthreads();

    // ================= DC =================
    for (int i = tid; i < NDWT; i += 256) row[i] = dc0in[base + i];
    __syncthreads();
    pool25<false>(row, pool, tid);
    __syncthreads();
    float msum2 = 0.f;
    for (int l = tid; l < NDWT; l += 256) {
        int pi = l - 12; pi = pi < 0 ? 0 : (pi > 697 ? 697 : pi);
        float m = pool[pi];
        msum2 += m;
        xc[l] = row[l] - m;
    }
    float m_all2 = blockSum256(msum2, red) * (1.f / 722.f);
    __syncthreads();
    pool25<true>(xc, pool, tid);
    __syncthreads();
    float ssum2 = 0.f;
    for (int l = tid; l < NDWT; l += 256) {
        int pi = l - 12; pi = pi < 0 ? 0 : (pi > 697 ? 697 : pi);
        float sd = pool[pi] + 1e-5f;
        ssum2 += sd;
        dcp[base + l] = xc[l] / sd;
    }
    float s_all2 = blockSum256(ssum2, red) * (1.f / 722.f);
    if (tid == 0) { stat[2 * RTOT + r] = m_all2; stat[3 * RTOT + r] = s_all2; }
    for (int l = tid; l < KP1; l += 256) {
        if (l < NDWT) {
            float m = row[l] - xc[l];
            int pi = l - 12; pi = pi < 0 ? 0 : (pi > 697 ? 697 : pi);
            float sd = pool[pi] + 1e-5f;
            cent[2 * CS + baseP + l] = f2bf(m - m_all2);
            cent[3 * CS + baseP + l] = f2bf(sd - s_all2);
        } else { cent[2 * CS + baseP + l] = 0; cent[3 * CS + baseP + l] = 0; }
    }
}

// ---------------- FFT-722 (mixed radix 2 x 19 x 19), forward, in LDS, packed-f32 math ----------------
// Incremental twiddles: stage1 w_j = W19^{j*t}; stage2 w_rr = W722^{2k*rr}. No scattered LDS twiddle reads.
__device__ void fft722_dev(f32x2* X, f32x2* T, f32x2* OUT, const f32x2* Wt, const f32x2* W19) {
    const int tid = threadIdx.x;
    for (int q = tid; q < NDWT; q += 256) {
        int p = (q >= 361) ? 1 : 0;
        int rem = q - 361 * p;
        int rr = rem / 19, t = rem - rr * 19;
        f32x2 step = W19[t];
        f32x2 w = {1.f, 0.f};
        f32x2 s = {0.f, 0.f};
        const f32x2* xp = X + 2 * rr + p;
        for (int j = 0; j < 19; j++) {
            cmac(s, xp[38 * j], w);
            w = cmul(w, step);
        }
        T[q] = s;
    }
    __syncthreads();
    for (int q = tid; q < NDWT; q += 256) {
        int p = (q >= 361) ? 1 : 0;
        int k = q - 361 * p;
        int t = k % 19;
        f32x2 step = Wt[2 * k];
        f32x2 w = {1.f, 0.f};
        f32x2 s = {0.f, 0.f};
        const f32x2* Ap = T + p * 361 + t;
        for (int rr = 0; rr < 19; rr++) {
            cmac(s, Ap[19 * rr], w);
            w = cmul(w, step);
        }
        X[q] = s;
    }
    __syncthreads();
    for (int k = tid; k < 361; k += 256) {
        f32x2 e = X[k], o = X[361 + k], w = Wt[k];
        f32x2 tt = {0.f, 0.f};
        cmac(tt, o, w);
        OUT[k] = e + tt;
        OUT[361 + k] = e - tt;
    }
    __syncthreads();
}

// ---------------- fused: packed FFT(acn + i*dc), radix-select top-362, mix, ifft ----------------
__global__ __launch_bounds__(256) void fft_mix_kernel(const float* __restrict__ acn,
                                                      float* __restrict__ dcp,
                                                      const f32x2* __restrict__ Wtab) {
    __shared__ f32x2 Wt[NDWT];
    __shared__ f32x2 W19s[19];
    __shared__ f32x2 B1[NDWT];
    __shared__ f32x2 B2[NDWT];
    __shared__ f32x2 B3[NDWT];
    __shared__ float smag[NDWT];
    __shared__ int   flags[NDWT];
    __shared__ unsigned hist[256];
    __shared__ unsigned suf[256];
    __shared__ int excl[256];
    __shared__ unsigned sh_digit, sh_rem;
    const int r = blockIdx.x, tid = threadIdx.x;
    const size_t base = (size_t)r * NDWT;

    for (int i = tid; i < NDWT; i += 256) Wt[i] = Wtab[i];
    if (tid < 19) W19s[tid] = Wtab[38 * tid];
    for (int i = tid; i < NDWT; i += 256) B1[i] = f32x2{acn[base + i], dcp[base + i]};
    __syncthreads();
    fft722_dev(B1, B2, B3, Wt, W19s);     // Z in B3
    // unpack: acF -> B1, dcF -> B2
    for (int k = tid; k < 362; k += 256) {
        int m = (NDWT - k) % NDWT;
        f32x2 zk = B3[k], zm = B3[m];
        f32x2 ak = {0.5f * (zk.x + zm.x), 0.5f * (zk.y - zm.y)};
        f32x2 dk = {0.5f * (zk.y + zm.y), 0.5f * (zm.x - zk.x)};
        B1[k] = ak; B2[k] = dk;
        smag[k] = ak.x * ak.x + ak.y * ak.y;
        if (m != k) {
            f32x2 am = {0.5f * (zm.x + zk.x), 0.5f * (zm.y - zk.y)};
            f32x2 dm = {0.5f * (zm.y + zk.y), 0.5f * (zk.x - zm.x)};
            B1[m] = am; B2[m] = dm;
            smag[m] = am.x * am.x + am.y * am.y;
        }
    }
    __syncthreads();

    // ---- radix-select: pivot = 362nd largest mag^2 ----
    unsigned prefix = 0, rem = NFREQ;
    for (int shift = 24; shift >= 0; shift -= 8) {
        hist[tid] = 0;
        __syncthreads();
        unsigned hm = (shift == 24) ? 0u : (0xFFFFFFFFu << (shift + 8));
        for (int i = tid; i < NDWT; i += 256) {
            unsigned b = __float_as_uint(smag[i]);
            if ((b & hm) == prefix) atomicAdd(&hist[(b >> shift) & 255], 1u);
        }
        __syncthreads();
        suf[tid] = hist[tid];
        __syncthreads();
        for (int off = 1; off < 256; off <<= 1) {
            unsigned v = (tid + off < 256) ? suf[tid + off] : 0;
            __syncthreads();
            suf[tid] += v;
            __syncthreads();
        }
        unsigned Shere = suf[tid];
        unsigned Snext = (tid < 255) ? suf[tid + 1] : 0;
        if (Shere >= rem && Snext < rem) { sh_digit = (unsigned)tid; sh_rem = rem - Snext; }
        __syncthreads();
        prefix |= (sh_digit << shift);
        rem = sh_rem;
        __syncthreads();
    }
    for (int i = tid; i < NDWT; i += 256)
        flags[i] = (__float_as_uint(smag[i]) > prefix) ? 1 : 0;
    int c0 = tid * 3, cnt = 0;
    #pragma unroll
    for (int j = 0; j < 3; j++) {
        int i = c0 + j;
        if (i < NDWT && __float_as_uint(smag[i]) == prefix) cnt++;
    }
    excl[tid] = cnt;
    __syncthreads();
    for (int off = 1; off < 256; off <<= 1) {
        int v = (tid >= off) ? excl[tid - off] : 0;
        __syncthreads();
        excl[tid] += v;
        __syncthreads();
    }
    int myexc = excl[tid] - cnt, o = 0;
    #pragma unroll
    for (int j = 0; j < 3; j++) {
        int i = c0 + j;
        if (i < NDWT && __float_as_uint(smag[i]) == prefix) {
            if (myexc + o < (int)rem) flags[i] = 1;
            o++;
        }
    }
    __syncthreads();

    // mix and conjugate (ifft via forward fft of conj)
    for (int i = tid; i < NDWT; i += 256) {
        f32x2 d = B2[i];
        if (flags[i]) { f32x2 a = B1[i]; d.x = 0.5f * (a.x + d.x); d.y = 0.5f * (a.y + d.y); }
        B3[i] = f32x2{d.x, -d.y};
    }
    __syncthreads();
    fft722_dev(B3, B1, B2, Wt, W19s);
    for (int i = tid; i < NDWT; i += 256) dcp[base + i] = B2[i].x * (1.f / 722.f);
}

// ---------------- merged inverse DWT for mean/std heads ----------------
__global__ __launch_bounds__(256) void iwt_heads_kernel(const float* __restrict__ heads,
                                                        float* __restrict__ out_mean,
                                                        float* __restrict__ out_std) {
    const int z = blockIdx.z;  // 0: mean (chains 0,2)  1: std (chains 1,3)
    const int r = blockIdx.x;
    const int t = blockIdx.y * 256 + threadIdx.x;
    if (t >= 720) return;
    const size_t HR = (size_t)RTOT * NHEAD;
    const float* lp = heads + (size_t)z * HR + (size_t)r * NHEAD;
    const float* hp = heads + (size_t)(2 + z) * HR + (size_t)r * NHEAD;
    float* out = (z ? out_std : out_mean) + (size_t)r * 720;
    float s = 0.f;
    if (t & 1) {
        int j0 = (t - 1) >> 1;
        #pragma unroll
        for (int i = 0; i < 3; i++) s += lp[j0 + i] * c_lo[2 * i] + hp[j0 + i] * c_hi[2 * i];
    } else {
        int j0 = t >> 1;
        #pragma unroll
        for (int i = 0; i < 3; i++) s += lp[j0 + i] * c_lo[2 * i + 1] + hp[j0 + i] * c_hi[2 * i + 1];
    }
    out[t] = s;
}

// ---------------- inverse DWT -> xr, bf16 reshaped (131072 x 96, cols 90..95 zero) ----------------
__global__ __launch_bounds__(256) void iwt_xr_kernel(const float* __restrict__ lo,
                                                     const float* __restrict__ hi,
                                                     unsigned short* __restrict__ xrbf) {
    const int r = blockIdx.x;
    const int t = blockIdx.y * 256 + threadIdx.x;
    if (blockIdx.y == 0 && threadIdx.x < 96) {
        int sub = threadIdx.x / 6, c = 90 + threadIdx.x % 6;
        xrbf[((size_t)r * 16 + sub) * 96 + c] = 0;
    }
    if (t >= LSEQ) return;
    const float* lp = lo + (size_t)r * NDWT;
    const float* hp = hi + (size_t)r * NDWT;
    float s = 0.f;
    if (t & 1) {
        int j0 = (t - 1) >> 1;
        #pragma unroll
        for (int i = 0; i < 3; i++) s += lp[j0 + i] * c_lo[2 * i] + hp[j0 + i] * c_hi[2 * i];
    } else {
        int j0 = t >> 1;
        #pragma unroll
        for (int i = 0; i < 3; i++) s += lp[j0 + i] * c_lo[2 * i + 1] + hp[j0 + i] * c_hi[2 * i + 1];
    }
    xrbf[((size_t)r * 16 + t / 90) * 96 + (t % 90)] = f2bf(s);
}

// ---------------- z-batched bf16 MFMA GEMM: C[z] = A[z] @ W[z]^T, 128x128 tile, BK=32 ----------------
// EPI: 0 bf16 plain, 1 bf16 relu, 4 f32 +cbias[col], 5 f32 per-z head epilogue (+bias; std adds relu+1e-5)
struct ZPtrs { const unsigned short* p[4]; };
template <int EPI>
__global__ __launch_bounds__(256) void mfma_gemm_z(
    const unsigned short* __restrict__ A, int lda, size_t zsA,
    ZPtrs Wz, int ldw,
    void* __restrict__ Cout, int ldc, size_t zsC, int Nc,
    const float* __restrict__ biasBase, const float* __restrict__ cbias,
    int Ksteps) {
    __shared__ unsigned short As[128 * 32];
    __shared__ unsigned short Bs[128 * 32];
    const int z = blockIdx.z;
    const unsigned short* Az = A + (size_t)z * zsA;
    const unsigned short* W = Wz.p[z];
    const int tid = threadIdx.x;
    const int lane = tid & 63, wid = tid >> 6;
    const int bm = blockIdx.x * 128, bn = blockIdx.y * 128;
    const int wr = (wid >> 1) * 64, wc = (wid & 1) * 64;
    f32x4 acc[4][4] = {};
    const int srow = (lane >> 2);
    const int scol = (lane & 3) * 8;

    for (int ks = 0; ks < Ksteps; ks++) {
        const int k0 = ks * 32;
        #pragma unroll
        for (int c = 0; c < 2; c++) {
            const int chunk = wid * 2 + c;
            const int row = chunk * 16 + srow;
            const unsigned short* ga = Az + (size_t)(bm + row) * lda + k0 + scol;
            const unsigned short* gb = W + (size_t)(bn + row) * ldw + k0 + scol;
            __builtin_amdgcn_global_load_lds(
                (const __attribute__((address_space(1))) unsigned int*)ga,
                (__attribute__((address_space(3))) unsigned int*)(As + chunk * 512), 16, 0, 0);
            __builtin_amdgcn_global_load_lds(
                (const __attribute__((address_space(1))) unsigned int*)gb,
                (__attribute__((address_space(3))) unsigned int*)(Bs + chunk * 512), 16, 0, 0);
        }
        __syncthreads();
        bf16x8 af[4], bfr[4];
        const int kof = (lane >> 4) * 8;
        #pragma unroll
        for (int m = 0; m < 4; m++)
            af[m] = *reinterpret_cast<const bf16x8*>(&As[(wr + m * 16 + (lane & 15)) * 32 + kof]);
        #pragma unroll
        for (int n = 0; n < 4; n++)
            bfr[n] = *reinterpret_cast<const bf16x8*>(&Bs[(wc + n * 16 + (lane & 15)) * 32 + kof]);
        #pragma unroll
        for (int m = 0; m < 4; m++)
            #pragma unroll
            for (int n = 0; n < 4; n++)
                acc[m][n] = __builtin_amdgcn_mfma_f32_16x16x32_bf16(af[m], bfr[n], acc[m][n], 0, 0, 0);
        __syncthreads();
    }

    unsigned short* Cb = (unsigned short*)Cout + (size_t)z * zsC;
    float* Cf = (float*)Cout + (size_t)z * zsC;
    const int crow0 = bm + wr + (lane >> 4) * 4;
    const int ccol0 = bn + wc + (lane & 15);
    #pragma unroll
    for (int m = 0; m < 4; m++) {
        #pragma unroll
        for (int n = 0; n < 4; n++) {
            const int col = ccol0 + n * 16;
            if (col < Nc) {
                #pragma unroll
                for (int q = 0; q < 4; q++) {
                    const int row = crow0 + m * 16 + q;
                    float v = acc[m][n][q];
                    if (EPI == 0) {
                        Cb[(size_t)row * ldc + col] = f2bf(v);
                    } else if (EPI == 1) {
                        Cb[(size_t)row * ldc + col] = f2bf(fmaxf(v, 0.f));
                    } else if (EPI == 4) {
                        Cf[(size_t)row * ldc + col] = v + cbias[col];
                    } else { // 5
                        float ob = biasBase[(size_t)z * RTOT + row];
                        if (z & 1) v = fmaxf(v + ob, 0.f) + 1e-5f;
                        else       v += ob;
                        Cf[(size_t)row * ldc + col] = v;
                    }
                }
            }
        }
    }
}

extern "C" void kernel_launch(void* const* d_in, const int* in_sizes, int n_in,
                              void* d_out, int out_size, void* d_ws, size_t ws_size,
                              hipStream_t stream) {
    const float* x = (const float*)d_in[0];
    const float* latent_w = (const float*)d_in[1];
    int p0;
    const float* latent_b;
    if (n_in > 2 && in_sizes[2] == 512) { latent_b = (const float*)d_in[2]; p0 = 3; }
    else                                { latent_b = (const float*)d_in[18]; p0 = 2; }

    // ---------------- workspace layout ----------------
    char* wp = (char*)d_ws;
    auto alloc = [&](size_t bytes) { char* p = wp; wp += (bytes + 255) & ~(size_t)255; return p; };
    const size_t RN = (size_t)RTOT * NDWT;
    float* acn  = (float*)alloc(RN * 4);
    float* dcb  = (float*)alloc(RN * 4);
    float* acp  = (float*)alloc(RN * 4);
    float* stat = (float*)alloc(4 * RTOT * 4);
    float2* Wtab = (float2*)alloc(NDWT * 8);
    unsigned short* cent  = (unsigned short*)alloc((size_t)4 * RTOT * KP1 * 2);   // 48.2 MB
    unsigned short* mlpB4 = (unsigned short*)alloc((size_t)4 * RTOT * 512 * 2);   // 33.5 MB
    unsigned short* mlpA4 = (unsigned short*)alloc((size_t)4 * RTOT * 1024 * 2);  // 67.1 MB
    unsigned short* mlpC4 = (unsigned short*)alloc((size_t)4 * RTOT * 512 * 2);   // 33.5 MB
    // aliases (lifetimes disjoint): heads (47.5 MB fp32) over mlpB4+mlpA4 (used after L3);
    // xrbf (25.2 MB) over mlpC4 (used after L4).
    float* heads = (float*)mlpB4;
    unsigned short* xrbf = mlpC4;
    unsigned short *projW[4], *w1W[4], *w2W[4], *predW[4];
    for (int z = 0; z < 4; z++) {
        projW[z] = (unsigned short*)alloc((size_t)512 * KP1 * 2);
        w1W[z]   = (unsigned short*)alloc((size_t)1024 * 512 * 2);
        w2W[z]   = (unsigned short*)alloc((size_t)512 * 1024 * 2);
        predW[z] = (unsigned short*)alloc((size_t)384 * 512 * 2);
    }
    unsigned short* latwb = (unsigned short*)alloc((size_t)512 * 96 * 2);
    (void)ws_size;

    // ---------------- single batched weight convert ----------------
    CvtArgs ca;
    int si = 0;
    for (int z = 0; z < 4; z++) {
        int branch = z >> 1, isStd = z & 1, wb = p0 + branch * 8;
        ca.d[si++] = {(const float*)d_in[wb + isStd],         projW[z], 512, NDWT, 512, KP1};
        ca.d[si++] = {(const float*)d_in[wb + 2 + 2 * isStd], w1W[z], 1024, 512, 1024, 512};
        ca.d[si++] = {(const float*)d_in[wb + 3 + 2 * isStd], w2W[z], 512, 1024, 512, 1024};
        ca.d[si++] = {(const float*)d_in[wb + 6 + isStd],     predW[z], NHEAD, 512, 384, 512};
    }
    ca.d[16] = {latent_w, latwb, 512, 90, 512, 96};
    cvt_all_kernel<<<dim3(2048, 17), dim3(256), 0, stream>>>(ca);

    wtab_kernel<<<dim3(3), dim3(256), 0, stream>>>(Wtab);
    dwt_kernel<<<dim3(64, 46), dim3(128, 4), 0, stream>>>(x, acn, dcb);
    rowstats_kernel<<<dim3(RTOT), dim3(256), 0, stream>>>(acn, dcb, acn, acp, dcb, cent, stat);
    fft_mix_kernel<<<dim3(RTOT), dim3(256), 0, stream>>>(acn, dcb, (const f32x2*)Wtab);

    // ---------------- 4 MLP chains, z-batched ----------------
    ZPtrs Zp = {{projW[0], projW[1], projW[2], projW[3]}};
    ZPtrs Z1 = {{w1W[0], w1W[1], w1W[2], w1W[3]}};
    ZPtrs Z2 = {{w2W[0], w2W[1], w2W[2], w2W[3]}};
    ZPtrs Zh = {{predW[0], predW[1], predW[2], predW[3]}};
    mfma_gemm_z<0><<<dim3(64, 4, 4), dim3(256), 0, stream>>>(
        cent, KP1, (size_t)RTOT * KP1, Zp, KP1, mlpB4, 512, (size_t)RTOT * 512, 512, nullptr, nullptr, KP1 / 32);
    mfma_gemm_z<1><<<dim3(64, 8, 4), dim3(256), 0, stream>>>(
        mlpB4, 512, (size_t)RTOT * 512, Z1, 512, mlpA4, 1024, (size_t)RTOT * 1024, 1024, nullptr, nullptr, 16);
    mfma_gemm_z<0><<<dim3(64, 4, 4), dim3(256), 0, stream>>>(
        mlpA4, 1024, (size_t)RTOT * 1024, Z2, 1024, mlpC4, 512, (size_t)RTOT * 512, 512, nullptr, nullptr, 32);
    mfma_gemm_z<5><<<dim3(64, 3, 4), dim3(256), 0, stream>>>(
        mlpC4, 512, (size_t)RTOT * 512, Zh, 512, heads, NHEAD, (size_t)RTOT * NHEAD, NHEAD, stat, nullptr, 16);

    float* out = (float*)d_out;
    float* out_mean = out + (size_t)67108864;           // 64*128*16*512
    float* out_std  = out_mean + (size_t)5898240;       // 64*128*720
    iwt_heads_kernel<<<dim3(RTOT, 3, 2), dim3(256), 0, stream>>>(heads, out_mean, out_std);
    iwt_xr_kernel<<<dim3(RTOT, 6), dim3(256), 0, stream>>>(acp, dcb, xrbf);

    // emb = xr(131072 x 90) @ latent_w^T (512 x 90) + latent_b
    ZPtrs Zl = {{latwb, latwb, latwb, latwb}};
    mfma_gemm_z<4><<<dim3(1024, 4, 1), dim3(256), 0, stream>>>(
        xrbf, 96, 0, Zl, 96, out, 512, 0, 512, nullptr, latent_b, 3);
}

// Round 4
// 648.459 us; speedup vs baseline: 7.0307x; 1.0369x over previous
//
#include <hip/hip_runtime.h>
#include <cmath>

#define RTOT 8192        // B*C rows
#define NDWT 722         // SEQ_LEN/2+2
#define KP1  736         // NDWT padded to 32
#define LSEQ 1440
#define NHEAD 362        // PRED_LEN/2+2
#define NFREQ 362

typedef __bf16 bf16x8 __attribute__((ext_vector_type(8)));
typedef float f32x4 __attribute__((ext_vector_type(4)));
typedef float f32x2 __attribute__((ext_vector_type(2)));

__device__ __forceinline__ unsigned short f2bf(float f) {
    unsigned u = __float_as_uint(f);
    u += 0x7fffu + ((u >> 16) & 1u);
    return (unsigned short)(u >> 16);
}

// complex MAC: s += a*w  (2x v_pk_fma_f32 via op_sel)
__device__ __forceinline__ void cmac(f32x2& s, f32x2 a, f32x2 w) {
    asm("v_pk_fma_f32 %0, %1, %2, %0 op_sel:[0,0,0] op_sel_hi:[0,1,1]\n\t"
        "v_pk_fma_f32 %0, %1, %2, %0 op_sel:[1,1,0] op_sel_hi:[1,0,1] neg_lo:[0,1,0]"
        : "+v"(s) : "v"(a), "v"(w));
}
// complex mul: r = a*b (v_pk_mul + v_pk_fma)
__device__ __forceinline__ f32x2 cmul(f32x2 a, f32x2 b) {
    f32x2 r;
    asm("v_pk_mul_f32 %0, %1, %2 op_sel:[0,0] op_sel_hi:[0,1]\n\t"
        "v_pk_fma_f32 %0, %1, %2, %0 op_sel:[1,1,0] op_sel_hi:[1,0,1] neg_lo:[0,1,0]"
        : "=&v"(r) : "v"(a), "v"(b));
    return r;
}

__constant__ float c_lo[6] = {0.035226291882100656f, -0.08544127388224149f, -0.13501102001039084f,
                              0.4598775021193313f, 0.8068915093133388f, 0.3326705529509569f};
__constant__ float c_hi[6] = {-0.3326705529509569f, 0.8068915093133388f, -0.4598775021193313f,
                              -0.13501102001039084f, 0.08544127388224149f, 0.035226291882100656f};

// ---------------- twiddle table: W^m = exp(-2*pi*i*m/722) ----------------
__global__ void wtab_kernel(float2* __restrict__ Wtab) {
    int m = blockIdx.x * blockDim.x + threadIdx.x;
    if (m < NDWT) {
        double ang = -2.0 * 3.141592653589793238462643383279502884 * (double)m / (double)NDWT;
        Wtab[m] = make_float2((float)cos(ang), (float)sin(ang));
    }
}

// ---------------- batched weight fp32 -> bf16 with zero padding (one dispatch) ----------------
struct CvtDesc { const float* src; unsigned short* dst; int N, K, Np, Kp; };
struct CvtArgs { CvtDesc d[17]; };
__global__ __launch_bounds__(256) void cvt_all_kernel(CvtArgs a) {
    CvtDesc d = a.d[blockIdx.y];
    int idx = blockIdx.x * 256 + threadIdx.x;
    int tot = d.Np * d.Kp;
    if (idx >= tot) return;
    int r = idx / d.Kp, c = idx - r * d.Kp;
    float v = (r < d.N && c < d.K) ? d.src[(size_t)r * d.K + c] : 0.f;
    d.dst[idx] = f2bf(v);
}

// ---------------- DWT: x (64,1440,128) -> ac0, dc0 (8192,722) ----------------
__global__ __launch_bounds__(512) void dwt_kernel(const float* __restrict__ x,
                                                  float* __restrict__ ac0,
                                                  float* __restrict__ dc0) {
    int b = blockIdx.x;
    int c = threadIdx.x;                       // 0..127
    int t0 = blockIdx.y * 16 + threadIdx.y * 4;
    for (int i = 0; i < 4; i++) {
        int t = t0 + i;
        if (t >= NDWT) break;
        float slo = 0.f, shi = 0.f;
        #pragma unroll
        for (int j = 0; j < 6; j++) {
            int l = 2 * t + 1 - j;
            float v = (l >= 0 && l < LSEQ) ? x[((size_t)b * LSEQ + l) * 128 + c] : 0.f;
            slo += v * c_lo[j];
            shi += v * c_hi[j];
        }
        size_t o = ((size_t)b * 128 + c) * NDWT + t;
        ac0[o] = slo;
        dc0[o] = shi;
    }
}

__device__ __forceinline__ float blockSum256(float v, float* red) {
    #pragma unroll
    for (int o = 32; o > 0; o >>= 1) v += __shfl_down(v, o, 64);
    int lane = threadIdx.x & 63, wid = threadIdx.x >> 6;
    __syncthreads();
    if (lane == 0) red[wid] = v;
    __syncthreads();
    return red[0] + red[1] + red[2] + red[3];
}

// sliding-window 25-tap mean over rowv[0..721] -> pool[0..697]; 3 outputs/thread
template <bool ABS>
__device__ __forceinline__ void pool25(const float* rowv, float* pool, int tid) {
    int i0 = tid * 3;
    if (i0 < 698) {
        float s25 = 0.f;
        #pragma unroll
        for (int j = 0; j < 25; j++) { float v = rowv[i0 + j]; s25 += ABS ? fabsf(v) : v; }
        pool[i0] = s25 * (1.f / 25.f);
        #pragma unroll
        for (int qq = 1; qq < 3; qq++) {
            int i = i0 + qq;
            if (i < 698) {
                float vin = rowv[i + 24], vout = rowv[i - 1];
                s25 += (ABS ? fabsf(vin) : vin) - (ABS ? fabsf(vout) : vout);
                pool[i] = s25 * (1.f / 25.f);
            }
        }
    }
}

// ---------------- per-row stats: inst_norm, mov_norm x2, centered bf16 outputs ----------------
__global__ __launch_bounds__(256) void rowstats_kernel(
    const float* __restrict__ ac0in, const float* __restrict__ dc0in,
    float* __restrict__ acn,   // aliases ac0in
    float* __restrict__ acp,
    float* __restrict__ dcp,   // aliases dc0in
    unsigned short* __restrict__ cent,  // [4][RTOT][KP1]: mcac, scac, mcdc, scdc
    float* __restrict__ stat /* [4][8192] */) {
    __shared__ float row[NDWT];
    __shared__ float xc[NDWT];
    __shared__ float pool[698];
    __shared__ float red[4];
    const int r = blockIdx.x, tid = threadIdx.x;
    const size_t base = (size_t)r * NDWT;
    const size_t baseP = (size_t)r * KP1;
    const size_t CS = (size_t)RTOT * KP1;

    // ================= AC =================
    for (int i = tid; i < NDWT; i += 256) row[i] = ac0in[base + i];
    __syncthreads();
    float s = 0.f;
    for (int i = tid; i < NDWT; i += 256) s += row[i];
    float mean = blockSum256(s, red) * (1.f / 722.f);
    s = 0.f;
    for (int i = tid; i < NDWT; i += 256) s += row[i] - mean;
    float m2 = blockSum256(s, red) * (1.f / 722.f);
    s = 0.f;
    for (int i = tid; i < NDWT; i += 256) { float d = row[i] - mean - m2; s += d * d; }
    float var = blockSum256(s, red) * (1.f / 722.f);
    float inv = 1.f / sqrtf(var + 1e-5f);
    for (int i = tid; i < NDWT; i += 256) acn[base + i] = (row[i] - mean) * inv;

    pool25<false>(row, pool, tid);
    __syncthreads();
    float msum = 0.f;
    for (int l = tid; l < NDWT; l += 256) {
        int pi = l - 12; pi = pi < 0 ? 0 : (pi > 697 ? 697 : pi);
        float m = pool[pi];
        msum += m;
        xc[l] = row[l] - m;
    }
    float m_all = blockSum256(msum, red) * (1.f / 722.f);
    __syncthreads();
    pool25<true>(xc, pool, tid);
    __syncthreads();
    float ssum = 0.f;
    for (int l = tid; l < NDWT; l += 256) {
        int pi = l - 12; pi = pi < 0 ? 0 : (pi > 697 ? 697 : pi);
        float sd = pool[pi] + 1e-5f;
        ssum += sd;
        acp[base + l] = xc[l] / sd;
    }
    float s_all = blockSum256(ssum, red) * (1.f / 722.f);
    if (tid == 0) { stat[r] = m_all; stat[RTOT + r] = s_all; }
    for (int l = tid; l < KP1; l += 256) {
        if (l < NDWT) {
            float m = row[l] - xc[l];
            int pi = l - 12; pi = pi < 0 ? 0 : (pi > 697 ? 697 : pi);
            float sd = pool[pi] + 1e-5f;
            cent[baseP + l]      = f2bf(m - m_all);
            cent[CS + baseP + l] = f2bf(sd - s_all);
        } else { cent[baseP + l] = 0; cent[CS + baseP + l] = 0; }
    }
    __syncthreads();

    // ================= DC =================
    for (int i = tid; i < NDWT; i += 256) row[i] = dc0in[base + i];
    __syncthreads();
    pool25<false>(row, pool, tid);
    __syncthreads();
    float msum2 = 0.f;
    for (int l = tid; l < NDWT; l += 256) {
        int pi = l - 12; pi = pi < 0 ? 0 : (pi > 697 ? 697 : pi);
        float m = pool[pi];
        msum2 += m;
        xc[l] = row[l] - m;
    }
    float m_all2 = blockSum256(msum2, red) * (1.f / 722.f);
    __syncthreads();
    pool25<true>(xc, pool, tid);
    __syncthreads();
    float ssum2 = 0.f;
    for (int l = tid; l < NDWT; l += 256) {
        int pi = l - 12; pi = pi < 0 ? 0 : (pi > 697 ? 697 : pi);
        float sd = pool[pi] + 1e-5f;
        ssum2 += sd;
        dcp[base + l] = xc[l] / sd;
    }
    float s_all2 = blockSum256(ssum2, red) * (1.f / 722.f);
    if (tid == 0) { stat[2 * RTOT + r] = m_all2; stat[3 * RTOT + r] = s_all2; }
    for (int l = tid; l < KP1; l += 256) {
        if (l < NDWT) {
            float m = row[l] - xc[l];
            int pi = l - 12; pi = pi < 0 ? 0 : (pi > 697 ? 697 : pi);
            float sd = pool[pi] + 1e-5f;
            cent[2 * CS + baseP + l] = f2bf(m - m_all2);
            cent[3 * CS + baseP + l] = f2bf(sd - s_all2);
        } else { cent[2 * CS + baseP + l] = 0; cent[3 * CS + baseP + l] = 0; }
    }
}

// ---------------- FFT-722 (mixed radix 2 x 19 x 19), forward, IN-PLACE in X, scratch T ----------------
// Dual-accumulator DFT-19 loops (two independent dependency chains), incremental twiddles.
__device__ void fft722_dev(f32x2* X, f32x2* T, const f32x2* Wt, const f32x2* W19) {
    const int tid = threadIdx.x;
    // Stage 1: X (scattered) -> T
    for (int q = tid; q < NDWT; q += 256) {
        int p = (q >= 361) ? 1 : 0;
        int rem = q - 361 * p;
        int rr = rem / 19, t = rem - rr * 19;
        f32x2 step = W19[t];
        f32x2 step2 = cmul(step, step);
        f32x2 w0 = {1.f, 0.f}, w1 = step;
        f32x2 s0 = {0.f, 0.f}, s1 = {0.f, 0.f};
        const f32x2* xp = X + 2 * rr + p;
        #pragma unroll
        for (int j = 0; j < 9; j++) {
            cmac(s0, xp[38 * (2 * j)], w0);     w0 = cmul(w0, step2);
            cmac(s1, xp[38 * (2 * j + 1)], w1); w1 = cmul(w1, step2);
        }
        cmac(s0, xp[38 * 18], w0);
        T[q] = s0 + s1;
    }
    __syncthreads();
    // Stage 2: T -> X
    for (int q = tid; q < NDWT; q += 256) {
        int p = (q >= 361) ? 1 : 0;
        int k = q - 361 * p;
        int t = k % 19;
        f32x2 step = Wt[2 * k];
        f32x2 step2 = cmul(step, step);
        f32x2 w0 = {1.f, 0.f}, w1 = step;
        f32x2 s0 = {0.f, 0.f}, s1 = {0.f, 0.f};
        const f32x2* Ap = T + p * 361 + t;
        #pragma unroll
        for (int j = 0; j < 9; j++) {
            cmac(s0, Ap[19 * (2 * j)], w0);     w0 = cmul(w0, step2);
            cmac(s1, Ap[19 * (2 * j + 1)], w1); w1 = cmul(w1, step2);
        }
        cmac(s0, Ap[19 * 18], w0);
        X[q] = s0 + s1;
    }
    __syncthreads();
    // Stage 3: radix-2 combine, in place (pairwise k <-> 361+k)
    for (int k = tid; k < 361; k += 256) {
        f32x2 e = X[k], o = X[361 + k], w = Wt[k];
        f32x2 tt = {0.f, 0.f};
        cmac(tt, o, w);
        X[k] = e + tt;
        X[361 + k] = e - tt;
    }
    __syncthreads();
}

// ---------------- fused: packed FFT(acn + i*dc), radix-select top-362, mix, ifft ----------------
__global__ __launch_bounds__(256) void fft_mix_kernel(const float* __restrict__ acn,
                                                      float* __restrict__ dcp,
                                                      const f32x2* __restrict__ Wtab) {
    __shared__ f32x2 Wt[NDWT];
    __shared__ f32x2 W19s[19];
    __shared__ f32x2 B1[NDWT];
    __shared__ f32x2 B2[NDWT];
    __shared__ float smag[NDWT];   // mag^2 during select; 0/1 flags afterwards
    __shared__ unsigned hist[256];
    __shared__ unsigned suf[256];  // suffix-scan scratch; reused for equal-rank scan
    __shared__ unsigned sh_digit, sh_rem;
    const int r = blockIdx.x, tid = threadIdx.x;
    const size_t base = (size_t)r * NDWT;

    for (int i = tid; i < NDWT; i += 256) Wt[i] = Wtab[i];
    if (tid < 19) W19s[tid] = Wtab[38 * tid];
    for (int i = tid; i < NDWT; i += 256) B1[i] = f32x2{acn[base + i], dcp[base + i]};
    __syncthreads();
    fft722_dev(B1, B2, Wt, W19s);         // Z in B1 (in place)
    // unpack pairwise in place: acF -> B1, dcF -> B2
    for (int k = tid; k < 362; k += 256) {
        int m = (NDWT - k) % NDWT;
        f32x2 zk = B1[k], zm = B1[m];
        f32x2 ak = {0.5f * (zk.x + zm.x), 0.5f * (zk.y - zm.y)};
        f32x2 dk = {0.5f * (zk.y + zm.y), 0.5f * (zm.x - zk.x)};
        B1[k] = ak; B2[k] = dk;
        smag[k] = ak.x * ak.x + ak.y * ak.y;
        if (m != k) {
            f32x2 am = {0.5f * (zm.x + zk.x), 0.5f * (zm.y - zk.y)};
            f32x2 dm = {0.5f * (zm.y + zk.y), 0.5f * (zk.x - zm.x)};
            B1[m] = am; B2[m] = dm;
            smag[m] = am.x * am.x + am.y * am.y;
        }
    }
    __syncthreads();

    // ---- radix-select: pivot = 362nd largest mag^2 (bits monotone for non-neg floats) ----
    unsigned prefix = 0, rem = NFREQ;
    for (int shift = 24; shift >= 0; shift -= 8) {
        hist[tid] = 0;
        __syncthreads();
        unsigned hm = (shift == 24) ? 0u : (0xFFFFFFFFu << (shift + 8));
        for (int i = tid; i < NDWT; i += 256) {
            unsigned b = __float_as_uint(smag[i]);
            if ((b & hm) == prefix) atomicAdd(&hist[(b >> shift) & 255], 1u);
        }
        __syncthreads();
        suf[tid] = hist[tid];
        __syncthreads();
        for (int off = 1; off < 256; off <<= 1) {
            unsigned v = (tid + off < 256) ? suf[tid + off] : 0;
            __syncthreads();
            suf[tid] += v;
            __syncthreads();
        }
        unsigned Shere = suf[tid];
        unsigned Snext = (tid < 255) ? suf[tid + 1] : 0;
        if (Shere >= rem && Snext < rem) { sh_digit = (unsigned)tid; sh_rem = rem - Snext; }
        __syncthreads();
        prefix |= (sh_digit << shift);
        rem = sh_rem;
        __syncthreads();
    }
    // equal-rank bookkeeping: thread owns chunk [3*tid, 3*tid+3)
    int c0 = tid * 3, cnt = 0;
    #pragma unroll
    for (int j = 0; j < 3; j++) {
        int i = c0 + j;
        if (i < NDWT && __float_as_uint(smag[i]) == prefix) cnt++;
    }
    suf[tid] = (unsigned)cnt;
    __syncthreads();
    for (int off = 1; off < 256; off <<= 1) {
        unsigned v = (tid >= off) ? suf[tid - off] : 0;
        __syncthreads();
        suf[tid] += v;
        __syncthreads();
    }
    int myexc = (int)suf[tid] - cnt, o = 0;
    // write flags in place over smag (each thread touches only its own chunk)
    #pragma unroll
    for (int j = 0; j < 3; j++) {
        int i = c0 + j;
        if (i < NDWT) {
            unsigned b = __float_as_uint(smag[i]);
            int f = (b > prefix) ? 1 : 0;
            if (b == prefix) { if ((unsigned)(myexc + o) < rem) f = 1; o++; }
            smag[i] = f ? 1.f : 0.f;
        }
    }
    __syncthreads();

    // mix and conjugate in place (ifft via forward fft of conj)
    for (int i = tid; i < NDWT; i += 256) {
        f32x2 d = B2[i];
        if (smag[i] != 0.f) { f32x2 a = B1[i]; d.x = 0.5f * (a.x + d.x); d.y = 0.5f * (a.y + d.y); }
        B1[i] = f32x2{d.x, -d.y};
    }
    __syncthreads();
    fft722_dev(B1, B2, Wt, W19s);
    for (int i = tid; i < NDWT; i += 256) dcp[base + i] = B1[i].x * (1.f / 722.f);
}

// ---------------- merged inverse DWT for mean/std heads ----------------
__global__ __launch_bounds__(256) void iwt_heads_kernel(const float* __restrict__ heads,
                                                        float* __restrict__ out_mean,
                                                        float* __restrict__ out_std) {
    const int z = blockIdx.z;  // 0: mean (chains 0,2)  1: std (chains 1,3)
    const int r = blockIdx.x;
    const int t = blockIdx.y * 256 + threadIdx.x;
    if (t >= 720) return;
    const size_t HR = (size_t)RTOT * NHEAD;
    const float* lp = heads + (size_t)z * HR + (size_t)r * NHEAD;
    const float* hp = heads + (size_t)(2 + z) * HR + (size_t)r * NHEAD;
    float* out = (z ? out_std : out_mean) + (size_t)r * 720;
    float s = 0.f;
    if (t & 1) {
        int j0 = (t - 1) >> 1;
        #pragma unroll
        for (int i = 0; i < 3; i++) s += lp[j0 + i] * c_lo[2 * i] + hp[j0 + i] * c_hi[2 * i];
    } else {
        int j0 = t >> 1;
        #pragma unroll
        for (int i = 0; i < 3; i++) s += lp[j0 + i] * c_lo[2 * i + 1] + hp[j0 + i] * c_hi[2 * i + 1];
    }
    out[t] = s;
}

// ---------------- inverse DWT -> xr, bf16 reshaped (131072 x 96, cols 90..95 zero) ----------------
__global__ __launch_bounds__(256) void iwt_xr_kernel(const float* __restrict__ lo,
                                                     const float* __restrict__ hi,
                                                     unsigned short* __restrict__ xrbf) {
    const int r = blockIdx.x;
    const int t = blockIdx.y * 256 + threadIdx.x;
    if (blockIdx.y == 0 && threadIdx.x < 96) {
        int sub = threadIdx.x / 6, c = 90 + threadIdx.x % 6;
        xrbf[((size_t)r * 16 + sub) * 96 + c] = 0;
    }
    if (t >= LSEQ) return;
    const float* lp = lo + (size_t)r * NDWT;
    const float* hp = hi + (size_t)r * NDWT;
    float s = 0.f;
    if (t & 1) {
        int j0 = (t - 1) >> 1;
        #pragma unroll
        for (int i = 0; i < 3; i++) s += lp[j0 + i] * c_lo[2 * i] + hp[j0 + i] * c_hi[2 * i];
    } else {
        int j0 = t >> 1;
        #pragma unroll
        for (int i = 0; i < 3; i++) s += lp[j0 + i] * c_lo[2 * i + 1] + hp[j0 + i] * c_hi[2 * i + 1];
    }
    xrbf[((size_t)r * 16 + t / 90) * 96 + (t % 90)] = f2bf(s);
}

// ---------------- z-batched bf16 MFMA GEMM: C[z] = A[z] @ W[z]^T, 128x128 tile, BK=32 ----------------
// EPI: 0 bf16 plain, 1 bf16 relu, 4 f32 +cbias[col], 5 f32 per-z head epilogue (+bias; std adds relu+1e-5)
struct ZPtrs { const unsigned short* p[4]; };
template <int EPI>
__global__ __launch_bounds__(256) void mfma_gemm_z(
    const unsigned short* __restrict__ A, int lda, size_t zsA,
    ZPtrs Wz, int ldw,
    void* __restrict__ Cout, int ldc, size_t zsC, int Nc,
    const float* __restrict__ biasBase, const float* __restrict__ cbias,
    int Ksteps) {
    __shared__ unsigned short As[128 * 32];
    __shared__ unsigned short Bs[128 * 32];
    const int z = blockIdx.z;
    const unsigned short* Az = A + (size_t)z * zsA;
    const unsigned short* W = Wz.p[z];
    const int tid = threadIdx.x;
    const int lane = tid & 63, wid = tid >> 6;
    const int bm = blockIdx.x * 128, bn = blockIdx.y * 128;
    const int wr = (wid >> 1) * 64, wc = (wid & 1) * 64;
    f32x4 acc[4][4] = {};
    const int srow = (lane >> 2);
    const int scol = (lane & 3) * 8;

    for (int ks = 0; ks < Ksteps; ks++) {
        const int k0 = ks * 32;
        #pragma unroll
        for (int c = 0; c < 2; c++) {
            const int chunk = wid * 2 + c;
            const int row = chunk * 16 + srow;
            const unsigned short* ga = Az + (size_t)(bm + row) * lda + k0 + scol;
            const unsigned short* gb = W + (size_t)(bn + row) * ldw + k0 + scol;
            __builtin_amdgcn_global_load_lds(
                (const __attribute__((address_space(1))) unsigned int*)ga,
                (__attribute__((address_space(3))) unsigned int*)(As + chunk * 512), 16, 0, 0);
            __builtin_amdgcn_global_load_lds(
                (const __attribute__((address_space(1))) unsigned int*)gb,
                (__attribute__((address_space(3))) unsigned int*)(Bs + chunk * 512), 16, 0, 0);
        }
        __syncthreads();
        bf16x8 af[4], bfr[4];
        const int kof = (lane >> 4) * 8;
        #pragma unroll
        for (int m = 0; m < 4; m++)
            af[m] = *reinterpret_cast<const bf16x8*>(&As[(wr + m * 16 + (lane & 15)) * 32 + kof]);
        #pragma unroll
        for (int n = 0; n < 4; n++)
            bfr[n] = *reinterpret_cast<const bf16x8*>(&Bs[(wc + n * 16 + (lane & 15)) * 32 + kof]);
        #pragma unroll
        for (int m = 0; m < 4; m++)
            #pragma unroll
            for (int n = 0; n < 4; n++)
                acc[m][n] = __builtin_amdgcn_mfma_f32_16x16x32_bf16(af[m], bfr[n], acc[m][n], 0, 0, 0);
        __syncthreads();
    }

    unsigned short* Cb = (unsigned short*)Cout + (size_t)z * zsC;
    float* Cf = (float*)Cout + (size_t)z * zsC;
    const int crow0 = bm + wr + (lane >> 4) * 4;
    const int ccol0 = bn + wc + (lane & 15);
    #pragma unroll
    for (int m = 0; m < 4; m++) {
        #pragma unroll
        for (int n = 0; n < 4; n++) {
            const int col = ccol0 + n * 16;
            if (col < Nc) {
                #pragma unroll
                for (int q = 0; q < 4; q++) {
                    const int row = crow0 + m * 16 + q;
                    float v = acc[m][n][q];
                    if (EPI == 0) {
                        Cb[(size_t)row * ldc + col] = f2bf(v);
                    } else if (EPI == 1) {
                        Cb[(size_t)row * ldc + col] = f2bf(fmaxf(v, 0.f));
                    } else if (EPI == 4) {
                        Cf[(size_t)row * ldc + col] = v + cbias[col];
                    } else { // 5
                        float ob = biasBase[(size_t)z * RTOT + row];
                        if (z & 1) v = fmaxf(v + ob, 0.f) + 1e-5f;
                        else       v += ob;
                        Cf[(size_t)row * ldc + col] = v;
                    }
                }
            }
        }
    }
}

extern "C" void kernel_launch(void* const* d_in, const int* in_sizes, int n_in,
                              void* d_out, int out_size, void* d_ws, size_t ws_size,
                              hipStream_t stream) {
    const float* x = (const float*)d_in[0];
    const float* latent_w = (const float*)d_in[1];
    int p0;
    const float* latent_b;
    if (n_in > 2 && in_sizes[2] == 512) { latent_b = (const float*)d_in[2]; p0 = 3; }
    else                                { latent_b = (const float*)d_in[18]; p0 = 2; }

    // ---------------- workspace layout ----------------
    char* wp = (char*)d_ws;
    auto alloc = [&](size_t bytes) { char* p = wp; wp += (bytes + 255) & ~(size_t)255; return p; };
    const size_t RN = (size_t)RTOT * NDWT;
    float* acn  = (float*)alloc(RN * 4);
    float* dcb  = (float*)alloc(RN * 4);
    float* acp  = (float*)alloc(RN * 4);
    float* stat = (float*)alloc(4 * RTOT * 4);
    float2* Wtab = (float2*)alloc(NDWT * 8);
    unsigned short* cent  = (unsigned short*)alloc((size_t)4 * RTOT * KP1 * 2);   // 48.2 MB
    unsigned short* mlpB4 = (unsigned short*)alloc((size_t)4 * RTOT * 512 * 2);   // 33.5 MB
    unsigned short* mlpA4 = (unsigned short*)alloc((size_t)4 * RTOT * 1024 * 2);  // 67.1 MB
    unsigned short* mlpC4 = (unsigned short*)alloc((size_t)4 * RTOT * 512 * 2);   // 33.5 MB
    // aliases (lifetimes disjoint): heads (47.5 MB fp32) over mlpB4+mlpA4 (used after L3);
    // xrbf (25.2 MB) over mlpC4 (used after L4).
    float* heads = (float*)mlpB4;
    unsigned short* xrbf = mlpC4;
    unsigned short *projW[4], *w1W[4], *w2W[4], *predW[4];
    for (int z = 0; z < 4; z++) {
        projW[z] = (unsigned short*)alloc((size_t)512 * KP1 * 2);
        w1W[z]   = (unsigned short*)alloc((size_t)1024 * 512 * 2);
        w2W[z]   = (unsigned short*)alloc((size_t)512 * 1024 * 2);
        predW[z] = (unsigned short*)alloc((size_t)384 * 512 * 2);
    }
    unsigned short* latwb = (unsigned short*)alloc((size_t)512 * 96 * 2);
    (void)ws_size;

    // ---------------- single batched weight convert ----------------
    CvtArgs ca;
    int si = 0;
    for (int z = 0; z < 4; z++) {
        int branch = z >> 1, isStd = z & 1, wb = p0 + branch * 8;
        ca.d[si++] = {(const float*)d_in[wb + isStd],         projW[z], 512, NDWT, 512, KP1};
        ca.d[si++] = {(const float*)d_in[wb + 2 + 2 * isStd], w1W[z], 1024, 512, 1024, 512};
        ca.d[si++] = {(const float*)d_in[wb + 3 + 2 * isStd], w2W[z], 512, 1024, 512, 1024};
        ca.d[si++] = {(const float*)d_in[wb + 6 + isStd],     predW[z], NHEAD, 512, 384, 512};
    }
    ca.d[16] = {latent_w, latwb, 512, 90, 512, 96};
    cvt_all_kernel<<<dim3(2048, 17), dim3(256), 0, stream>>>(ca);

    wtab_kernel<<<dim3(3), dim3(256), 0, stream>>>(Wtab);
    dwt_kernel<<<dim3(64, 46), dim3(128, 4), 0, stream>>>(x, acn, dcb);
    rowstats_kernel<<<dim3(RTOT), dim3(256), 0, stream>>>(acn, dcb, acn, acp, dcb, cent, stat);
    fft_mix_kernel<<<dim3(RTOT), dim3(256), 0, stream>>>(acn, dcb, (const f32x2*)Wtab);

    // ---------------- 4 MLP chains, z-batched ----------------
    ZPtrs Zp = {{projW[0], projW[1], projW[2], projW[3]}};
    ZPtrs Z1 = {{w1W[0], w1W[1], w1W[2], w1W[3]}};
    ZPtrs Z2 = {{w2W[0], w2W[1], w2W[2], w2W[3]}};
    ZPtrs Zh = {{predW[0], predW[1], predW[2], predW[3]}};
    mfma_gemm_z<0><<<dim3(64, 4, 4), dim3(256), 0, stream>>>(
        cent, KP1, (size_t)RTOT * KP1, Zp, KP1, mlpB4, 512, (size_t)RTOT * 512, 512, nullptr, nullptr, KP1 / 32);
    mfma_gemm_z<1><<<dim3(64, 8, 4), dim3(256), 0, stream>>>(
        mlpB4, 512, (size_t)RTOT * 512, Z1, 512, mlpA4, 1024, (size_t)RTOT * 1024, 1024, nullptr, nullptr, 16);
    mfma_gemm_z<0><<<dim3(64, 4, 4), dim3(256), 0, stream>>>(
        mlpA4, 1024, (size_t)RTOT * 1024, Z2, 1024, mlpC4, 512, (size_t)RTOT * 512, 512, nullptr, nullptr, 32);
    mfma_gemm_z<5><<<dim3(64, 3, 4), dim3(256), 0, stream>>>(
        mlpC4, 512, (size_t)RTOT * 512, Zh, 512, heads, NHEAD, (size_t)RTOT * NHEAD, NHEAD, stat, nullptr, 16);

    float* out = (float*)d_out;
    float* out_mean = out + (size_t)67108864;           // 64*128*16*512
    float* out_std  = out_mean + (size_t)5898240;       // 64*128*720
    iwt_heads_kernel<<<dim3(RTOT, 3, 2), dim3(256), 0, stream>>>(heads, out_mean, out_std);
    iwt_xr_kernel<<<dim3(RTOT, 6), dim3(256), 0, stream>>>(acp, dcb, xrbf);

    // emb = xr(131072 x 90) @ latent_w^T (512 x 90) + latent_b
    ZPtrs Zl = {{latwb, latwb, latwb, latwb}};
    mfma_gemm_z<4><<<dim3(1024, 4, 1), dim3(256), 0, stream>>>(
        xrbf, 96, 0, Zl, 96, out, 512, 0, 512, nullptr, latent_b, 3);
}